// Round 15
// baseline (521.399 us; speedup 1.0000x reference)
//
#include <hip/hip_runtime.h>
#include <hip/hip_bf16.h>
#include <math.h>

// ---------------------------------------------------------------------------
// GAT 2-layer + classifier.
// R22: continuing R21's critical-path surgery (partB 92.8->79.7, total 458):
//      (1) partB phase-2 2-deep prefetch (next dst/src/ea in flight during
//          current edge's 128-FMA projection; +~18 VGPR, stays <=128);
//      (2) passC single-pass: offs computed globally by degree-count chain
//          (countN/scanA/scanBlk/finz, L2-resident atomics), passC loads
//          dbase from offs and only scatters; dlArr stream deleted.
//      agg/gemms/classifier/hist/scanB unchanged (controls).
// ---------------------------------------------------------------------------

#define CHUNK 2048

typedef __attribute__((ext_vector_type(8))) short short8;
typedef __attribute__((ext_vector_type(4))) float floatx4;
typedef __attribute__((ext_vector_type(2))) float floatx2;

__device__ __forceinline__ unsigned short f2bf(float f) {
  unsigned u = __float_as_uint(f);
  unsigned r = u + 0x7FFFu + ((u >> 16) & 1u);
  return (unsigned short)(r >> 16);
}
__device__ __forceinline__ float bf2f(unsigned short b) {
  return __uint_as_float(((unsigned)b) << 16);
}

__global__ __launch_bounds__(512) void hist_kernel(const int* __restrict__ dst,
                                                   int* __restrict__ bucketCnt,
                                                   int* __restrict__ chunkHist,
                                                   int E, int NB) {
  __shared__ int hist[512];
  const int tid = threadIdx.x;
  hist[tid] = 0;
  __syncthreads();
  const int e0 = blockIdx.x * CHUNK, e1 = min(e0 + CHUNK, E);
  for (int e = e0 + tid; e < e1; e += 512) atomicAdd(&hist[dst[e] >> 7], 1);
  __syncthreads();
  chunkHist[(size_t)blockIdx.x * 512 + tid] = hist[tid];
  if (tid < NB && hist[tid]) atomicAdd(&bucketCnt[tid], hist[tid]);
}

__global__ __launch_bounds__(512) void scanB_kernel(const int* __restrict__ bucketCnt,
                                                    int* __restrict__ bucketOffs,
                                                    int* __restrict__ bucketPos,
                                                    int* __restrict__ offs,
                                                    int NB, int N, int E) {
  __shared__ int sc[512];
  const int tid = threadIdx.x;
  const int v = (tid < NB) ? bucketCnt[tid] : 0;
  sc[tid] = v;
  __syncthreads();
  for (int off = 1; off < 512; off <<= 1) {
    int t = (tid >= off) ? sc[tid - off] : 0;
    __syncthreads();
    sc[tid] += t;
    __syncthreads();
  }
  const int excl = sc[tid] - v;
  if (tid < NB) { bucketOffs[tid] = excl; bucketPos[tid] = excl; }
  if (tid == 0) { bucketOffs[NB] = E; offs[N] = E; }
}

// ---- global per-node degree scan (for passC single-pass) ----
__global__ __launch_bounds__(256) void countN_kernel(const int* __restrict__ dst,
                                                     int* __restrict__ cnt, int E) {
  int i = blockIdx.x * 256 + threadIdx.x;
  const int stride = gridDim.x * 256;
  for (; i < E; i += stride) atomicAdd(&cnt[dst[i]], 1);
}

__global__ __launch_bounds__(256) void scanA_kernel(const int* __restrict__ cnt,
                                                    int* __restrict__ offs,
                                                    int* __restrict__ blockSum, int N) {
  __shared__ int sc[256];
  const int tid = threadIdx.x;
  const int i = blockIdx.x * 256 + tid;
  const int v = (i < N) ? cnt[i] : 0;
  sc[tid] = v;
  __syncthreads();
  for (int off = 1; off < 256; off <<= 1) {
    int t = (tid >= off) ? sc[tid - off] : 0;
    __syncthreads();
    sc[tid] += t;
    __syncthreads();
  }
  if (i < N) offs[i] = sc[tid] - v;
  if (tid == 255) blockSum[blockIdx.x] = sc[255];
}

__global__ __launch_bounds__(256) void scanBlk_kernel(int* __restrict__ blockSum, int NBLK) {
  __shared__ int sc[256];
  const int tid = threadIdx.x;
  const int v = (tid < NBLK) ? blockSum[tid] : 0;
  sc[tid] = v;
  __syncthreads();
  for (int off = 1; off < 256; off <<= 1) {
    int t = (tid >= off) ? sc[tid - off] : 0;
    __syncthreads();
    sc[tid] += t;
    __syncthreads();
  }
  if (tid < NBLK) blockSum[tid] = sc[tid] - v;
}

__global__ __launch_bounds__(256) void finz_kernel(int* __restrict__ offs,
                                                   const int* __restrict__ blockSum, int N) {
  const int i = blockIdx.x * 256 + threadIdx.x;
  if (i < N) offs[i] += blockSum[i >> 8];
}

// Staged bucket partition fused with alpha projection (R21 structure +
// 2-deep prefetch in phase 2; dlArr stream removed).
__global__ __launch_bounds__(512) void partB_kernel(const int* __restrict__ src,
                                                    const int* __restrict__ dst,
                                                    const float* __restrict__ ea,
                                                    const float* __restrict__ ae1,
                                                    const float* __restrict__ We1,
                                                    const float* __restrict__ ae2,
                                                    const float* __restrict__ We2,
                                                    const int* __restrict__ chunkHist,
                                                    int* __restrict__ bucketPos,
                                                    int4* __restrict__ binned16,
                                                    int* __restrict__ binned4,
                                                    int E, int NB) {
  __shared__ float wa[128];
  __shared__ int lbase[513], gbase[512], lcnt[512];
  __shared__ int waveSum[8];
  __shared__ int4 stg16[CHUNK];
  __shared__ int stg4[CHUNK];
  const int tid = threadIdx.x;
  const int wv = tid >> 6;
  const int lane = tid & 63;
  const int e0 = blockIdx.x * CHUNK;
  const int e1 = min(e0 + CHUNK, E);
  lcnt[tid] = 0;
  if (tid < 128) {
    const float* aev = (tid < 64) ? ae1 : ae2;
    const float* Wev = (tid < 64) ? We1 : We2;
    const int h = (tid >> 4) & 3;
    const int d = tid & 15;
    float s = 0.f;
#pragma unroll
    for (int c = 0; c < 32; ++c) s += aev[h * 32 + c] * Wev[(h * 32 + c) * 16 + d];
    wa[tid] = s;
  }
  const int hv = chunkHist[(size_t)blockIdx.x * 512 + tid];
  int v = hv;
#pragma unroll
  for (int off = 1; off < 64; off <<= 1) {
    int t = __shfl_up(v, off);
    if (lane >= off) v += t;
  }
  if (lane == 63) waveSum[wv] = v;
  __syncthreads();
  int woff = 0;
#pragma unroll
  for (int i = 0; i < 8; ++i) woff += (i < wv) ? waveSum[i] : 0;
  lbase[tid + 1] = v + woff;
  if (tid == 0) lbase[0] = 0;
  if (tid < NB && hv > 0) gbase[tid] = atomicAdd(&bucketPos[tid], hv);
  __syncthreads();
  // phase 2: stage full payload with 2-deep prefetch
  {
    int e = e0 + tid;
    bool valid = (e < e1);
    int dcur = 0, scur = 0;
    float4 qa, qb, qc, qd;
    if (valid) {
      dcur = dst[e]; scur = src[e];
      const float4* p = (const float4*)(ea + (size_t)e * 16);
      qa = p[0]; qb = p[1]; qc = p[2]; qd = p[3];
    }
    while (valid) {
      const int en = e + 512;
      const bool vnext = (en < e1);
      int dnxt = 0, snxt = 0;
      float4 na, nb, nc, nd;
      if (vnext) {
        dnxt = dst[en]; snxt = src[en];
        const float4* p = (const float4*)(ea + (size_t)en * 16);
        na = p[0]; nb = p[1]; nc = p[2]; nd = p[3];
      }
      const int b = dcur >> 7;
      const int lr = atomicAdd(&lcnt[b], 1);
      float v16[16] = {qa.x, qa.y, qa.z, qa.w, qb.x, qb.y, qb.z, qb.w,
                       qc.x, qc.y, qc.z, qc.w, qd.x, qd.y, qd.z, qd.w};
      unsigned short rr[8];
#pragma unroll
      for (int h = 0; h < 8; ++h) {
        float sm = 0.f;
#pragma unroll
        for (int d2 = 0; d2 < 16; ++d2) sm += v16[d2] * wa[h * 16 + d2];
        rr[h] = f2bf(sm);
      }
      int4 pv;
      pv.x = (int)(((unsigned)(scur & 0xFFFF)) | ((unsigned)(dcur & 127) << 16) |
                   ((unsigned)b << 23));
      pv.y = (int)(((unsigned)rr[1] << 16) | rr[0]);
      pv.z = (int)(((unsigned)rr[3] << 16) | rr[2]);
      pv.w = (int)(((unsigned)rr[5] << 16) | rr[4]);
      const int sp = lbase[b] + lr;
      stg16[sp] = pv;
      stg4[sp] = (int)(((unsigned)rr[7] << 16) | rr[6]);
      e = en; valid = vnext; dcur = dnxt; scur = snxt;
      qa = na; qb = nb; qc = nc; qd = nd;
    }
  }
  __syncthreads();
  // phase 3: ordered scatter; bucket id read from payload
  const int total = e1 - e0;
  for (int t = tid; t < total; t += 512) {
    const int4 pv = stg16[t];
    const int b = (int)(((unsigned)pv.x) >> 23);
    const int g = gbase[b] + (t - lbase[b]);
    binned16[g] = pv;
    binned4[g] = stg4[t];
  }
}

// Single-pass: dbase loaded from global offs (degree scan); scatter only.
__global__ __launch_bounds__(256) void passC_kernel(const int4* __restrict__ binned16,
                                                    const int* __restrict__ binned4,
                                                    const int* __restrict__ bucketOffs,
                                                    const int* __restrict__ offs,
                                                    int* __restrict__ srcS,
                                                    uint2* __restrict__ aeS1,
                                                    uint2* __restrict__ aeS2, int N) {
  __shared__ int dbaseG[128], dpos[128];
  const int tid = threadIdx.x;
  const int b = blockIdx.x;
  const int bo = bucketOffs[b], be = bucketOffs[b + 1];
  const int m = be - bo;
  const int dcnt = min(128, N - (b << 7));
  if (tid < 128) {
    dpos[tid] = 0;
    dbaseG[tid] = (tid < dcnt) ? offs[(b << 7) + tid] : 0;
  }
  __syncthreads();
  for (int t = tid; t < m; t += 256) {
    const int4 v = binned16[bo + t];
    const int w4 = binned4[bo + t];
    const int dl = (v.x >> 16) & 127;
    const int p = dbaseG[dl] + atomicAdd(&dpos[dl], 1);
    srcS[p] = v.x & 0xFFFF;
    aeS1[p] = make_uint2((unsigned)v.y, (unsigned)v.z);
    aeS2[p] = make_uint2((unsigned)v.w, (unsigned)w4);
  }
}

// W1 -> bf16, W2 -> bf16, Wlin -> padded [48][128] bf16 hi+lo, one kernel.
__global__ __launch_bounds__(256) void cvtall_kernel(const float* __restrict__ W1,
                                                     unsigned short* __restrict__ Wb1,
                                                     const float* __restrict__ W2,
                                                     unsigned short* __restrict__ Wb2,
                                                     const float* __restrict__ Wlin,
                                                     unsigned short* __restrict__ whi,
                                                     unsigned short* __restrict__ wlo) {
  const int n1 = 128 * 64, n2 = 128 * 128, n3 = 48 * 128;
  int i = blockIdx.x * 256 + threadIdx.x;
  if (i < n1) {
    Wb1[i] = f2bf(W1[i]);
  } else if (i < n1 + n2) {
    Wb2[i - n1] = f2bf(W2[i - n1]);
  } else if (i < n1 + n2 + n3) {
    const int j = i - n1 - n2;
    float v = (j < 40 * 128) ? Wlin[j] : 0.f;
    unsigned short h = f2bf(v);
    whi[j] = h;
    wlo[j] = f2bf(v - bf2f(h));
  }
}

// Swapped-operand MFMA body (R16).
#define GEMM_MFMA_SWAPPED(KTOT, PA, PB)                                            \
  {                                                                                \
    for (int kc = 0; kc < (KTOT); kc += 32) {                                      \
      const int koff = kc + (quad << 3);                                           \
      short8 aw[2], bx[4];                                                         \
      _Pragma("unroll") for (int ct = 0; ct < 2; ++ct)                             \
        aw[ct] = *(const short8*)(&Bs[(w * 32 + ct * 16 + l15) * (PB) + koff]);    \
      _Pragma("unroll") for (int nt_ = 0; nt_ < 4; ++nt_)                          \
        bx[nt_] = *(const short8*)(&As[(nt_ * 16 + l15) * (PA) + koff]);           \
      _Pragma("unroll") for (int ct = 0; ct < 2; ++ct)                             \
        _Pragma("unroll") for (int nt_ = 0; nt_ < 4; ++nt_)                        \
          acc[ct][nt_] =                                                           \
              __builtin_amdgcn_mfma_f32_16x16x32_bf16(aw[ct], bx[nt_],             \
                                                      acc[ct][nt_], 0, 0, 0);      \
    }                                                                              \
  }

#define GEMM_WRITE_H_SWAPPED()                                                     \
  {                                                                                \
    _Pragma("unroll") for (int nt_ = 0; nt_ < 4; ++nt_) {                          \
      const int node = m0 + nt_ * 16 + l15;                                        \
      if (node < n) {                                                              \
        _Pragma("unroll") for (int ct = 0; ct < 2; ++ct) {                         \
          const int ch = w * 32 + ct * 16 + (quad << 2);                           \
          ushort4 o;                                                               \
          o.x = f2bf(acc[ct][nt_][0]); o.y = f2bf(acc[ct][nt_][1]);                \
          o.z = f2bf(acc[ct][nt_][2]); o.w = f2bf(acc[ct][nt_][3]);                \
          *(ushort4*)(H + (size_t)node * 128 + ch) = o;                            \
        }                                                                          \
      }                                                                            \
    }                                                                              \
  }

#define GEMM_SCORE_SWAPPED()                                                       \
  {                                                                                \
    float asv[2][4], adv[2][4];                                                    \
    _Pragma("unroll") for (int ct = 0; ct < 2; ++ct)                               \
      _Pragma("unroll") for (int r = 0; r < 4; ++r) {                              \
        const int c = w * 32 + ct * 16 + (quad << 2) + r;                          \
        asv[ct][r] = a_s[c]; adv[ct][r] = a_d[c];                                  \
      }                                                                            \
    _Pragma("unroll") for (int nt_ = 0; nt_ < 4; ++nt_) {                          \
      float ps = 0.f, pd = 0.f;                                                    \
      _Pragma("unroll") for (int ct = 0; ct < 2; ++ct)                             \
        _Pragma("unroll") for (int r = 0; r < 4; ++r) {                            \
          ps += acc[ct][nt_][r] * asv[ct][r];                                      \
          pd += acc[ct][nt_][r] * adv[ct][r];                                      \
        }                                                                          \
      ps += __shfl_xor(ps, 16); ps += __shfl_xor(ps, 32);                          \
      pd += __shfl_xor(pd, 16); pd += __shfl_xor(pd, 32);                          \
      if (lane < 16) {                                                             \
        const int node = m0 + nt_ * 16 + lane;                                     \
        if (node < n) {                                                            \
          ssc[(size_t)node * 4 + w] = ps;                                          \
          dsc[(size_t)node * 4 + w] = pd;                                          \
        }                                                                          \
      }                                                                            \
    }                                                                              \
  }

// Layer-1 GEMM: fp32 X (K=64), LDS-staged A (convert during stage) + B.
__global__ __launch_bounds__(256) void gemm_score_f32_kernel(const float* __restrict__ X,
                                                             const unsigned short* __restrict__ Wb,
                                                             const float* __restrict__ a_s,
                                                             const float* __restrict__ a_d,
                                                             unsigned short* __restrict__ H,
                                                             float* __restrict__ ssc,
                                                             float* __restrict__ dsc,
                                                             int n) {
  __shared__ unsigned short As[64 * 72];
  __shared__ unsigned short Bs[128 * 72];
  const int tid = threadIdx.x;
  const int w = tid >> 6;
  const int lane = tid & 63;
  const int m0 = blockIdx.x * 64;
  const int quad = lane >> 4;
  const int l15 = lane & 15;

#pragma unroll
  for (int it = 0; it < 4; ++it) {
    const int idx = it * 256 + tid;
    const int row = idx >> 4;
    const int c4 = (idx & 15) * 4;
    const int grow = min(m0 + row, n - 1);
    const float4 q = *(const float4*)(X + (size_t)grow * 64 + c4);
    unsigned short* dstp = &As[row * 72 + c4];
    dstp[0] = f2bf(q.x); dstp[1] = f2bf(q.y); dstp[2] = f2bf(q.z); dstp[3] = f2bf(q.w);
  }
#pragma unroll
  for (int it = 0; it < 4; ++it) {
    const int idx = it * 256 + tid;
    const int row = idx >> 3;
    const int c8 = (idx & 7) * 8;
    short8 v = *(const short8*)(Wb + (size_t)row * 64 + c8);
    *(short8*)(&Bs[row * 72 + c8]) = v;
  }
  __syncthreads();

  floatx4 acc[2][4];
#pragma unroll
  for (int ct = 0; ct < 2; ++ct)
#pragma unroll
    for (int nt_ = 0; nt_ < 4; ++nt_) acc[ct][nt_] = (floatx4)(0.f);

  GEMM_MFMA_SWAPPED(64, 72, 72)
  GEMM_WRITE_H_SWAPPED()
  GEMM_SCORE_SWAPPED()
}

// Layer-2 GEMM: bf16 X (K=128), LDS-staged A + B.
__global__ __launch_bounds__(256) void gemm_score_kernel(const unsigned short* __restrict__ X,
                                                         const unsigned short* __restrict__ Wb,
                                                         const float* __restrict__ a_s,
                                                         const float* __restrict__ a_d,
                                                         unsigned short* __restrict__ H,
                                                         float* __restrict__ ssc,
                                                         float* __restrict__ dsc,
                                                         int n) {
  __shared__ unsigned short As[64 * 136];
  __shared__ unsigned short Bs[128 * 136];
  const int tid = threadIdx.x;
  const int w = tid >> 6;
  const int lane = tid & 63;
  const int m0 = blockIdx.x * 64;
  const int quad = lane >> 4;
  const int l15 = lane & 15;

#pragma unroll
  for (int it = 0; it < 4; ++it) {
    const int idx = it * 256 + tid;
    const int row = idx >> 4;
    const int c8 = (idx & 15) * 8;
    const int grow = min(m0 + row, n - 1);
    short8 v = *(const short8*)(X + (size_t)grow * 128 + c8);
    *(short8*)(&As[row * 136 + c8]) = v;
  }
#pragma unroll
  for (int it = 0; it < 8; ++it) {
    const int idx = it * 256 + tid;
    const int row = idx >> 4;
    const int c8 = (idx & 15) * 8;
    short8 v = *(const short8*)(Wb + (size_t)row * 128 + c8);
    *(short8*)(&Bs[row * 136 + c8]) = v;
  }
  __syncthreads();

  floatx4 acc[2][4];
#pragma unroll
  for (int ct = 0; ct < 2; ++ct)
#pragma unroll
    for (int nt_ = 0; nt_ < 4; ++nt_) acc[ct][nt_] = (floatx4)(0.f);

  GEMM_MFMA_SWAPPED(128, 136, 136)
  GEMM_WRITE_H_SWAPPED()
  GEMM_SCORE_SWAPPED()
}

__device__ __forceinline__ float leaky02(float a) { return a > 0.f ? a : 0.2f * a; }
__device__ __forceinline__ float sel4(float4 v, int h) {
  return (h == 0) ? v.x : (h == 1) ? v.y : (h == 2) ? v.z : v.w;
}

// 1 wave per node (R8/R16 form — measured optimum). Phase B unroll-8,
// packed-fp32 accumulate.
__global__ __launch_bounds__(256) void agg_kernel(const unsigned short* __restrict__ hin,
                                                  const float* __restrict__ ssc,
                                                  const float* __restrict__ dsc,
                                                  const unsigned short* __restrict__ aeS,
                                                  const int* __restrict__ offs,
                                                  const int* __restrict__ srcS,
                                                  const float* __restrict__ bias,
                                                  unsigned short* __restrict__ hout, int n) {
  __shared__ int sbuf[4][64];
  __shared__ float pbuf[4][256];
  const int tid = threadIdx.x;
  const int wv = tid >> 6;
  const int lane = tid & 63;
  const int node = blockIdx.x * 4 + wv;
  if (node >= n) return;
  const int l32 = lane & 31;
  const int half = lane >> 5;
  const int ch4 = l32 * 4;
  const int headB = l32 >> 3;
  const float4 dv = *(const float4*)(dsc + (size_t)node * 4);
  float4 l4 = make_float4(0.f, 0.f, 0.f, 0.f);
  float4 sa = make_float4(0.f, 0.f, 0.f, 0.f);
  floatx2 acc01 = (floatx2)(0.f);
  floatx2 acc23 = (floatx2)(0.f);
  const int j0 = offs[node], j1 = offs[node + 1];

  for (int jc = j0; jc < j1; jc += 64) {
    const int len = min(64, j1 - jc);
    float4 p4 = make_float4(0.f, 0.f, 0.f, 0.f);
    int sv = 0;
    if (lane < len) {
      const int j = jc + lane;
      sv = srcS[j];
      const ushort4 aq = *(const ushort4*)(aeS + (size_t)j * 4);
      const float4 ae4 = make_float4(bf2f(aq.x), bf2f(aq.y), bf2f(aq.z), bf2f(aq.w));
      const float4 ss4 = *(const float4*)(ssc + (size_t)sv * 4);
      sa.x += ae4.x; sa.y += ae4.y; sa.z += ae4.z; sa.w += ae4.w;
      p4.x = __expf(leaky02(ss4.x + dv.x + ae4.x));
      p4.y = __expf(leaky02(ss4.y + dv.y + ae4.y));
      p4.z = __expf(leaky02(ss4.z + dv.z + ae4.z));
      p4.w = __expf(leaky02(ss4.w + dv.w + ae4.w));
    }
    sbuf[wv][lane] = sv;
    *(float4*)(&pbuf[wv][lane * 4]) = p4;
    l4.x += p4.x; l4.y += p4.y; l4.z += p4.z; l4.w += p4.w;
    int k = 0;
    for (; k + 8 <= len; k += 8) {
      int s[4];
      float p[4];
      uint2 d[4];
#pragma unroll
      for (int u = 0; u < 4; ++u) {
        const int kk = k + 2 * u + half;
        s[u] = sbuf[wv][kk];
        p[u] = pbuf[wv][kk * 4 + headB];
      }
#pragma unroll
      for (int u = 0; u < 4; ++u)
        d[u] = *(const uint2*)(hin + (size_t)s[u] * 128 + ch4);
#pragma unroll
      for (int u = 0; u < 4; ++u) {
        floatx2 p2; p2.x = p[u]; p2.y = p[u];
        floatx2 h01, h23;
        h01.x = __uint_as_float(d[u].x << 16);
        h01.y = __uint_as_float(d[u].x & 0xFFFF0000u);
        h23.x = __uint_as_float(d[u].y << 16);
        h23.y = __uint_as_float(d[u].y & 0xFFFF0000u);
        acc01 += p2 * h01;
        acc23 += p2 * h23;
      }
    }
    for (; k < len; k += 2) {
      int kk = k + half;
      if (kk < len) {
        int s = sbuf[wv][kk];
        float p = pbuf[wv][kk * 4 + headB];
        uint2 d = *(const uint2*)(hin + (size_t)s * 128 + ch4);
        floatx2 p2; p2.x = p; p2.y = p;
        floatx2 h01, h23;
        h01.x = __uint_as_float(d.x << 16);
        h01.y = __uint_as_float(d.x & 0xFFFF0000u);
        h23.x = __uint_as_float(d.y << 16);
        h23.y = __uint_as_float(d.y & 0xFFFF0000u);
        acc01 += p2 * h01;
        acc23 += p2 * h23;
      }
    }
  }

  float acc[4] = {acc01.x, acc01.y, acc23.x, acc23.y};
#pragma unroll
  for (int off = 32; off; off >>= 1) {
    sa.x += __shfl_xor(sa.x, off);
    sa.y += __shfl_xor(sa.y, off);
    sa.z += __shfl_xor(sa.z, off);
    sa.w += __shfl_xor(sa.w, off);
    l4.x += __shfl_xor(l4.x, off);
    l4.y += __shfl_xor(l4.y, off);
    l4.z += __shfl_xor(l4.z, off);
    l4.w += __shfl_xor(l4.w, off);
  }
#pragma unroll
  for (int i = 0; i < 4; ++i) acc[i] += __shfl_xor(acc[i], 32);

  const int deg = j1 - j0;
  const float invd = 1.f / fmaxf((float)deg, 1.f);
  const float ssn = ssc[(size_t)node * 4 + headB];
  const float aloop = leaky02(ssn + sel4(dv, headB) + sel4(sa, headB) * invd);
  const float pl = __expf(aloop);
  const float lF = sel4(l4, headB) + pl;
  const uint2 hd = *(const uint2*)(hin + (size_t)node * 128 + ch4);
  const float hv0 = __uint_as_float(hd.x << 16);
  const float hv1 = __uint_as_float(hd.x & 0xFFFF0000u);
  const float hv2 = __uint_as_float(hd.y << 16);
  const float hv3 = __uint_as_float(hd.y & 0xFFFF0000u);
  const float inv = 1.f / (lF + 1e-16f);
  const float4 bi = *(const float4*)(bias + ch4);
  const float o0 = fmaxf((acc[0] + pl * hv0) * inv + bi.x, 0.f);
  const float o1 = fmaxf((acc[1] + pl * hv1) * inv + bi.y, 0.f);
  const float o2 = fmaxf((acc[2] + pl * hv2) * inv + bi.z, 0.f);
  const float o3 = fmaxf((acc[3] + pl * hv3) * inv + bi.w, 0.f);
  if (half == 0) {
    ushort4 o;
    o.x = f2bf(o0); o.y = f2bf(o1); o.z = f2bf(o2); o.w = f2bf(o3);
    *(ushort4*)(hout + (size_t)node * 128 + ch4) = o;
  }
}

// Classifier as MFMA GEMM fused with log_softmax (R8).
__global__ __launch_bounds__(256) void classifier_kernel(const unsigned short* __restrict__ h,
                                                         const unsigned short* __restrict__ Whi,
                                                         const unsigned short* __restrict__ Wlo,
                                                         const float* __restrict__ blin,
                                                         float* __restrict__ out, int n) {
  const int w = threadIdx.x >> 6;
  const int lane = threadIdx.x & 63;
  const int quad = lane >> 4;
  const int l15 = lane & 15;
  const int row0 = blockIdx.x * 64 + w * 16;
  if (row0 >= n) return;
  int rowm = row0 + l15;
  if (rowm >= n) rowm = n - 1;
  floatx4 acc[3];
#pragma unroll
  for (int nt = 0; nt < 3; ++nt) acc[nt] = (floatx4)(0.f);
  const size_t hbase = (size_t)rowm * 128;
#pragma unroll
  for (int kc = 0; kc < 128; kc += 32) {
    const int koff = kc + (quad << 3);
    short8 a = *(const short8*)(h + hbase + koff);
#pragma unroll
    for (int nt = 0; nt < 3; ++nt) {
      short8 bh = *(const short8*)(Whi + (size_t)(nt * 16 + l15) * 128 + koff);
      short8 bl = *(const short8*)(Wlo + (size_t)(nt * 16 + l15) * 128 + koff);
      acc[nt] = __builtin_amdgcn_mfma_f32_16x16x32_bf16(a, bh, acc[nt], 0, 0, 0);
      acc[nt] = __builtin_amdgcn_mfma_f32_16x16x32_bf16(a, bl, acc[nt], 0, 0, 0);
    }
  }
  const float bl0 = blin[l15];
  const float bl1 = blin[16 + l15];
  const float bl2 = (l15 < 8) ? blin[32 + l15] : 0.f;
#pragma unroll
  for (int r = 0; r < 4; ++r) {
    const int rrow = row0 + (quad << 2) + r;
    const float v0 = acc[0][r] + bl0;
    const float v1 = acc[1][r] + bl1;
    const float v2 = (l15 < 8) ? (acc[2][r] + bl2) : -INFINITY;
    float m = fmaxf(v0, fmaxf(v1, v2));
#pragma unroll
    for (int off = 8; off; off >>= 1) m = fmaxf(m, __shfl_xor(m, off, 16));
    const float e2 = (l15 < 8) ? __expf(v2 - m) : 0.f;
    float s = __expf(v0 - m) + __expf(v1 - m) + e2;
#pragma unroll
    for (int off = 8; off; off >>= 1) s += __shfl_xor(s, off, 16);
    const float ls = m + __logf(s);
    if (rrow < n) {
      float* po = out + (size_t)rrow * 40;
      po[l15] = v0 - ls;
      po[16 + l15] = v1 - ls;
      if (l15 < 8) po[32 + l15] = v2 - ls;
    }
  }
}

extern "C" void kernel_launch(void* const* d_in, const int* in_sizes, int n_in,
                              void* d_out, int out_size, void* d_ws, size_t ws_size,
                              hipStream_t stream) {
  const float* x    = (const float*)d_in[0];
  const int*   eidx = (const int*)d_in[1];
  const float* ea   = (const float*)d_in[2];
  const float* W1   = (const float*)d_in[3];
  const float* as1  = (const float*)d_in[4];
  const float* ad1  = (const float*)d_in[5];
  const float* ae1w = (const float*)d_in[6];
  const float* We1  = (const float*)d_in[7];
  const float* b1   = (const float*)d_in[8];
  const float* W2   = (const float*)d_in[9];
  const float* as2  = (const float*)d_in[10];
  const float* ad2  = (const float*)d_in[11];
  const float* ae2w = (const float*)d_in[12];
  const float* We2  = (const float*)d_in[13];
  const float* b2   = (const float*)d_in[14];
  const float* Wlin = (const float*)d_in[15];
  const float* blin = (const float*)d_in[16];
  float* out = (float*)d_out;

  const int N = in_sizes[0] / 64;
  const int E = in_sizes[1] / 2;
  const int* src = eidx;
  const int* dst = eidx + E;
  const int NB = (N + 127) >> 7;
  const int gp = (E + CHUNK - 1) / CHUNK;
  const int NBLK = (N + 255) / 256;

  char* wsb = (char*)d_ws;
  size_t off = 0;
  auto alloc = [&](size_t bytes) -> void* {
    void* p = wsb + off;
    off = (off + bytes + 255) & ~(size_t)255;
    return p;
  };
  int* bucketCnt  = (int*)alloc(512 * 4);
  int* bucketOffs = (int*)alloc(513 * 4);
  int* bucketPos  = (int*)alloc(512 * 4);
  int* offs       = (int*)alloc((size_t)(N + 1) * 4);
  int* degCnt     = (int*)alloc((size_t)N * 4);
  int* blockSum   = (int*)alloc(256 * 4);
  int* chunkHist  = (int*)alloc((size_t)gp * 512 * 4);
  uint2* aeS1     = (uint2*)alloc((size_t)E * 8);
  uint2* aeS2     = (uint2*)alloc((size_t)E * 8);
  void* regC      = alloc((size_t)E * 16);          // binned16 -> hA
  int4* binned16  = (int4*)regC;
  unsigned short* hA = (unsigned short*)regC;       // N*256 <= E*16
  int* binned4    = (int*)alloc((size_t)E * 4);
  int* srcS       = (int*)alloc((size_t)E * 4);
  unsigned short* Wb1 = (unsigned short*)alloc(128 * 64 * 2);
  unsigned short* Wb2 = (unsigned short*)alloc(128 * 128 * 2);
  unsigned short* Wlh = (unsigned short*)alloc(48 * 128 * 2);
  unsigned short* Wll = (unsigned short*)alloc(48 * 128 * 2);
  float* ssc      = (float*)alloc((size_t)N * 4 * 4);
  float* dsc      = (float*)alloc((size_t)N * 4 * 4);
  unsigned short* hB = (unsigned short*)alloc((size_t)N * 128 * 2);

  const int gg = (N + 63) / 64;
  const int gs = (N + 3) / 4;
  const int ge = (E + 255) / 256;
  const int ncvt = 128 * 64 + 128 * 128 + 48 * 128;

  // ---- CSR bucket sort with fused alpha projection ----
  hipMemsetAsync(bucketCnt, 0, 512 * 4, stream);
  hipMemsetAsync(degCnt, 0, (size_t)N * 4, stream);
  hist_kernel<<<gp, 512, 0, stream>>>(dst, bucketCnt, chunkHist, E, NB);
  countN_kernel<<<2048, 256, 0, stream>>>(dst, degCnt, E);
  scanB_kernel<<<1, 512, 0, stream>>>(bucketCnt, bucketOffs, bucketPos, offs, NB, N, E);
  scanA_kernel<<<NBLK, 256, 0, stream>>>(degCnt, offs, blockSum, N);
  scanBlk_kernel<<<1, 256, 0, stream>>>(blockSum, NBLK);
  finz_kernel<<<NBLK, 256, 0, stream>>>(offs, blockSum, N);
  partB_kernel<<<gp, 512, 0, stream>>>(src, dst, ea, ae1w, We1, ae2w, We2, chunkHist,
                                       bucketPos, binned16, binned4, E, NB);
  passC_kernel<<<NB, 256, 0, stream>>>(binned16, binned4, bucketOffs, offs,
                                       srcS, aeS1, aeS2, N);

  // ---- weight conversions (one kernel) ----
  cvtall_kernel<<<(ncvt + 255) / 256, 256, 0, stream>>>(W1, Wb1, W2, Wb2, Wlin, Wlh, Wll);

  // ---- layer 1 (gemm + fused score) ----
  gemm_score_f32_kernel<<<gg, 256, 0, stream>>>(x, Wb1, as1, ad1, hA, ssc, dsc, N);
  agg_kernel<<<gs, 256, 0, stream>>>(hA, ssc, dsc, (const unsigned short*)aeS1, offs, srcS, b1, hB, N);

  // ---- layer 2 (gemm + fused score) ----
  gemm_score_kernel<<<gg, 256, 0, stream>>>(hB, Wb2, as2, ad2, hA, ssc, dsc, N);
  agg_kernel<<<gs, 256, 0, stream>>>(hA, ssc, dsc, (const unsigned short*)aeS2, offs, srcS, b2, hB, N);

  // ---- classifier + log_softmax ----
  classifier_kernel<<<gg, 256, 0, stream>>>(hB, Wlh, Wll, blin, out, N);
}

// Round 16
// 449.696 us; speedup vs baseline: 1.1594x; 1.1594x over previous
//
#include <hip/hip_runtime.h>
#include <hip/hip_bf16.h>
#include <math.h>

// ---------------------------------------------------------------------------
// GAT 2-layer + classifier.
// R23: R21 base (458.1us best) + partB 2-deep prefetch kept from R22.
//      R22's countN degree chain DELETED (70.5us, 50MB write amp from
//      random 4B atomics — R11's failure mode in miniature). passC reverted
//      to R21 form (dlArr count pass + scan + scatter, writes offs).
//      agg/gemms/classifier/hist/scanB unchanged (controls).
// ---------------------------------------------------------------------------

#define CHUNK 2048

typedef __attribute__((ext_vector_type(8))) short short8;
typedef __attribute__((ext_vector_type(4))) float floatx4;
typedef __attribute__((ext_vector_type(2))) float floatx2;

__device__ __forceinline__ unsigned short f2bf(float f) {
  unsigned u = __float_as_uint(f);
  unsigned r = u + 0x7FFFu + ((u >> 16) & 1u);
  return (unsigned short)(r >> 16);
}
__device__ __forceinline__ float bf2f(unsigned short b) {
  return __uint_as_float(((unsigned)b) << 16);
}

__global__ __launch_bounds__(512) void hist_kernel(const int* __restrict__ dst,
                                                   int* __restrict__ bucketCnt,
                                                   int* __restrict__ chunkHist,
                                                   int E, int NB) {
  __shared__ int hist[512];
  const int tid = threadIdx.x;
  hist[tid] = 0;
  __syncthreads();
  const int e0 = blockIdx.x * CHUNK, e1 = min(e0 + CHUNK, E);
  for (int e = e0 + tid; e < e1; e += 512) atomicAdd(&hist[dst[e] >> 7], 1);
  __syncthreads();
  chunkHist[(size_t)blockIdx.x * 512 + tid] = hist[tid];
  if (tid < NB && hist[tid]) atomicAdd(&bucketCnt[tid], hist[tid]);
}

__global__ __launch_bounds__(512) void scanB_kernel(const int* __restrict__ bucketCnt,
                                                    int* __restrict__ bucketOffs,
                                                    int* __restrict__ bucketPos,
                                                    int* __restrict__ offs,
                                                    int NB, int N, int E) {
  __shared__ int sc[512];
  const int tid = threadIdx.x;
  const int v = (tid < NB) ? bucketCnt[tid] : 0;
  sc[tid] = v;
  __syncthreads();
  for (int off = 1; off < 512; off <<= 1) {
    int t = (tid >= off) ? sc[tid - off] : 0;
    __syncthreads();
    sc[tid] += t;
    __syncthreads();
  }
  const int excl = sc[tid] - v;
  if (tid < NB) { bucketOffs[tid] = excl; bucketPos[tid] = excl; }
  if (tid == 0) { bucketOffs[NB] = E; offs[N] = E; }
}

// Staged bucket partition fused with alpha projection (R21 structure +
// 2-deep prefetch in phase 2; dlArr restored for passC's count pass).
__global__ __launch_bounds__(512) void partB_kernel(const int* __restrict__ src,
                                                    const int* __restrict__ dst,
                                                    const float* __restrict__ ea,
                                                    const float* __restrict__ ae1,
                                                    const float* __restrict__ We1,
                                                    const float* __restrict__ ae2,
                                                    const float* __restrict__ We2,
                                                    const int* __restrict__ chunkHist,
                                                    int* __restrict__ bucketPos,
                                                    int4* __restrict__ binned16,
                                                    int* __restrict__ binned4,
                                                    unsigned char* __restrict__ dlArr,
                                                    int E, int NB) {
  __shared__ float wa[128];
  __shared__ int lbase[513], gbase[512], lcnt[512];
  __shared__ int waveSum[8];
  __shared__ int4 stg16[CHUNK];
  __shared__ int stg4[CHUNK];
  const int tid = threadIdx.x;
  const int wv = tid >> 6;
  const int lane = tid & 63;
  const int e0 = blockIdx.x * CHUNK;
  const int e1 = min(e0 + CHUNK, E);
  lcnt[tid] = 0;
  if (tid < 128) {
    const float* aev = (tid < 64) ? ae1 : ae2;
    const float* Wev = (tid < 64) ? We1 : We2;
    const int h = (tid >> 4) & 3;
    const int d = tid & 15;
    float s = 0.f;
#pragma unroll
    for (int c = 0; c < 32; ++c) s += aev[h * 32 + c] * Wev[(h * 32 + c) * 16 + d];
    wa[tid] = s;
  }
  const int hv = chunkHist[(size_t)blockIdx.x * 512 + tid];
  int v = hv;
#pragma unroll
  for (int off = 1; off < 64; off <<= 1) {
    int t = __shfl_up(v, off);
    if (lane >= off) v += t;
  }
  if (lane == 63) waveSum[wv] = v;
  __syncthreads();
  int woff = 0;
#pragma unroll
  for (int i = 0; i < 8; ++i) woff += (i < wv) ? waveSum[i] : 0;
  lbase[tid + 1] = v + woff;
  if (tid == 0) lbase[0] = 0;
  if (tid < NB && hv > 0) gbase[tid] = atomicAdd(&bucketPos[tid], hv);
  __syncthreads();
  // phase 2: stage full payload with 2-deep prefetch
  {
    int e = e0 + tid;
    bool valid = (e < e1);
    int dcur = 0, scur = 0;
    float4 qa, qb, qc, qd;
    if (valid) {
      dcur = dst[e]; scur = src[e];
      const float4* p = (const float4*)(ea + (size_t)e * 16);
      qa = p[0]; qb = p[1]; qc = p[2]; qd = p[3];
    }
    while (valid) {
      const int en = e + 512;
      const bool vnext = (en < e1);
      int dnxt = 0, snxt = 0;
      float4 na, nb, nc, nd;
      if (vnext) {
        dnxt = dst[en]; snxt = src[en];
        const float4* p = (const float4*)(ea + (size_t)en * 16);
        na = p[0]; nb = p[1]; nc = p[2]; nd = p[3];
      }
      const int b = dcur >> 7;
      const int lr = atomicAdd(&lcnt[b], 1);
      float v16[16] = {qa.x, qa.y, qa.z, qa.w, qb.x, qb.y, qb.z, qb.w,
                       qc.x, qc.y, qc.z, qc.w, qd.x, qd.y, qd.z, qd.w};
      unsigned short rr[8];
#pragma unroll
      for (int h = 0; h < 8; ++h) {
        float sm = 0.f;
#pragma unroll
        for (int d2 = 0; d2 < 16; ++d2) sm += v16[d2] * wa[h * 16 + d2];
        rr[h] = f2bf(sm);
      }
      int4 pv;
      pv.x = (int)(((unsigned)(scur & 0xFFFF)) | ((unsigned)(dcur & 127) << 16) |
                   ((unsigned)b << 23));
      pv.y = (int)(((unsigned)rr[1] << 16) | rr[0]);
      pv.z = (int)(((unsigned)rr[3] << 16) | rr[2]);
      pv.w = (int)(((unsigned)rr[5] << 16) | rr[4]);
      const int sp = lbase[b] + lr;
      stg16[sp] = pv;
      stg4[sp] = (int)(((unsigned)rr[7] << 16) | rr[6]);
      e = en; valid = vnext; dcur = dnxt; scur = snxt;
      qa = na; qb = nb; qc = nc; qd = nd;
    }
  }
  __syncthreads();
  // phase 3: ordered scatter; bucket id read from payload
  const int total = e1 - e0;
  for (int t = tid; t < total; t += 512) {
    const int4 pv = stg16[t];
    const int b = (int)(((unsigned)pv.x) >> 23);
    const int g = gbase[b] + (t - lbase[b]);
    binned16[g] = pv;
    binned4[g] = stg4[t];
    dlArr[g] = (unsigned char)((pv.x >> 16) & 127);
  }
}

// Sort within bucket by dst; scatter srcS + both alpha arrays (R21 form).
__global__ __launch_bounds__(256) void passC_kernel(const int4* __restrict__ binned16,
                                                    const int* __restrict__ binned4,
                                                    const unsigned char* __restrict__ dlArr,
                                                    const int* __restrict__ bucketOffs,
                                                    int* __restrict__ srcS,
                                                    uint2* __restrict__ aeS1,
                                                    uint2* __restrict__ aeS2,
                                                    int* __restrict__ offs, int N) {
  __shared__ int cnt[128], dbase[129], dpos[128];
  const int tid = threadIdx.x;
  const int b = blockIdx.x;
  const int bo = bucketOffs[b], be = bucketOffs[b + 1];
  const int m = be - bo;
  if (tid < 128) { cnt[tid] = 0; dpos[tid] = 0; }
  __syncthreads();
  for (int t = tid; t < m; t += 256) atomicAdd(&cnt[dlArr[bo + t]], 1);
  __syncthreads();
  for (int off = 1; off < 128; off <<= 1) {
    int t = (tid < 128 && tid >= (unsigned)off) ? cnt[tid - off] : 0;
    __syncthreads();
    if (tid < 128) cnt[tid] += t;
    __syncthreads();
  }
  if (tid == 0) dbase[0] = 0;
  if (tid < 128) dbase[tid + 1] = cnt[tid];
  __syncthreads();
  const int dcnt = min(128, N - (b << 7));
  if (tid < dcnt) offs[(b << 7) + tid] = bo + dbase[tid];
  for (int t = tid; t < m; t += 256) {
    const int4 v = binned16[bo + t];
    const int w4 = binned4[bo + t];
    const int dl = (v.x >> 16) & 127;
    const int p = dbase[dl] + atomicAdd(&dpos[dl], 1);
    srcS[bo + p] = v.x & 0xFFFF;
    aeS1[bo + p] = make_uint2((unsigned)v.y, (unsigned)v.z);
    aeS2[bo + p] = make_uint2((unsigned)v.w, (unsigned)w4);
  }
}

// W1 -> bf16, W2 -> bf16, Wlin -> padded [48][128] bf16 hi+lo, one kernel.
__global__ __launch_bounds__(256) void cvtall_kernel(const float* __restrict__ W1,
                                                     unsigned short* __restrict__ Wb1,
                                                     const float* __restrict__ W2,
                                                     unsigned short* __restrict__ Wb2,
                                                     const float* __restrict__ Wlin,
                                                     unsigned short* __restrict__ whi,
                                                     unsigned short* __restrict__ wlo) {
  const int n1 = 128 * 64, n2 = 128 * 128, n3 = 48 * 128;
  int i = blockIdx.x * 256 + threadIdx.x;
  if (i < n1) {
    Wb1[i] = f2bf(W1[i]);
  } else if (i < n1 + n2) {
    Wb2[i - n1] = f2bf(W2[i - n1]);
  } else if (i < n1 + n2 + n3) {
    const int j = i - n1 - n2;
    float v = (j < 40 * 128) ? Wlin[j] : 0.f;
    unsigned short h = f2bf(v);
    whi[j] = h;
    wlo[j] = f2bf(v - bf2f(h));
  }
}

// Swapped-operand MFMA body (R16).
#define GEMM_MFMA_SWAPPED(KTOT, PA, PB)                                            \
  {                                                                                \
    for (int kc = 0; kc < (KTOT); kc += 32) {                                      \
      const int koff = kc + (quad << 3);                                           \
      short8 aw[2], bx[4];                                                         \
      _Pragma("unroll") for (int ct = 0; ct < 2; ++ct)                             \
        aw[ct] = *(const short8*)(&Bs[(w * 32 + ct * 16 + l15) * (PB) + koff]);    \
      _Pragma("unroll") for (int nt_ = 0; nt_ < 4; ++nt_)                          \
        bx[nt_] = *(const short8*)(&As[(nt_ * 16 + l15) * (PA) + koff]);           \
      _Pragma("unroll") for (int ct = 0; ct < 2; ++ct)                             \
        _Pragma("unroll") for (int nt_ = 0; nt_ < 4; ++nt_)                        \
          acc[ct][nt_] =                                                           \
              __builtin_amdgcn_mfma_f32_16x16x32_bf16(aw[ct], bx[nt_],             \
                                                      acc[ct][nt_], 0, 0, 0);      \
    }                                                                              \
  }

#define GEMM_WRITE_H_SWAPPED()                                                     \
  {                                                                                \
    _Pragma("unroll") for (int nt_ = 0; nt_ < 4; ++nt_) {                          \
      const int node = m0 + nt_ * 16 + l15;                                        \
      if (node < n) {                                                              \
        _Pragma("unroll") for (int ct = 0; ct < 2; ++ct) {                         \
          const int ch = w * 32 + ct * 16 + (quad << 2);                           \
          ushort4 o;                                                               \
          o.x = f2bf(acc[ct][nt_][0]); o.y = f2bf(acc[ct][nt_][1]);                \
          o.z = f2bf(acc[ct][nt_][2]); o.w = f2bf(acc[ct][nt_][3]);                \
          *(ushort4*)(H + (size_t)node * 128 + ch) = o;                            \
        }                                                                          \
      }                                                                            \
    }                                                                              \
  }

#define GEMM_SCORE_SWAPPED()                                                       \
  {                                                                                \
    float asv[2][4], adv[2][4];                                                    \
    _Pragma("unroll") for (int ct = 0; ct < 2; ++ct)                               \
      _Pragma("unroll") for (int r = 0; r < 4; ++r) {                              \
        const int c = w * 32 + ct * 16 + (quad << 2) + r;                          \
        asv[ct][r] = a_s[c]; adv[ct][r] = a_d[c];                                  \
      }                                                                            \
    _Pragma("unroll") for (int nt_ = 0; nt_ < 4; ++nt_) {                          \
      float ps = 0.f, pd = 0.f;                                                    \
      _Pragma("unroll") for (int ct = 0; ct < 2; ++ct)                             \
        _Pragma("unroll") for (int r = 0; r < 4; ++r) {                            \
          ps += acc[ct][nt_][r] * asv[ct][r];                                      \
          pd += acc[ct][nt_][r] * adv[ct][r];                                      \
        }                                                                          \
      ps += __shfl_xor(ps, 16); ps += __shfl_xor(ps, 32);                          \
      pd += __shfl_xor(pd, 16); pd += __shfl_xor(pd, 32);                          \
      if (lane < 16) {                                                             \
        const int node = m0 + nt_ * 16 + lane;                                     \
        if (node < n) {                                                            \
          ssc[(size_t)node * 4 + w] = ps;                                          \
          dsc[(size_t)node * 4 + w] = pd;                                          \
        }                                                                          \
      }                                                                            \
    }                                                                              \
  }

// Layer-1 GEMM: fp32 X (K=64), LDS-staged A (convert during stage) + B.
__global__ __launch_bounds__(256) void gemm_score_f32_kernel(const float* __restrict__ X,
                                                             const unsigned short* __restrict__ Wb,
                                                             const float* __restrict__ a_s,
                                                             const float* __restrict__ a_d,
                                                             unsigned short* __restrict__ H,
                                                             float* __restrict__ ssc,
                                                             float* __restrict__ dsc,
                                                             int n) {
  __shared__ unsigned short As[64 * 72];
  __shared__ unsigned short Bs[128 * 72];
  const int tid = threadIdx.x;
  const int w = tid >> 6;
  const int lane = tid & 63;
  const int m0 = blockIdx.x * 64;
  const int quad = lane >> 4;
  const int l15 = lane & 15;

#pragma unroll
  for (int it = 0; it < 4; ++it) {
    const int idx = it * 256 + tid;
    const int row = idx >> 4;
    const int c4 = (idx & 15) * 4;
    const int grow = min(m0 + row, n - 1);
    const float4 q = *(const float4*)(X + (size_t)grow * 64 + c4);
    unsigned short* dstp = &As[row * 72 + c4];
    dstp[0] = f2bf(q.x); dstp[1] = f2bf(q.y); dstp[2] = f2bf(q.z); dstp[3] = f2bf(q.w);
  }
#pragma unroll
  for (int it = 0; it < 4; ++it) {
    const int idx = it * 256 + tid;
    const int row = idx >> 3;
    const int c8 = (idx & 7) * 8;
    short8 v = *(const short8*)(Wb + (size_t)row * 64 + c8);
    *(short8*)(&Bs[row * 72 + c8]) = v;
  }
  __syncthreads();

  floatx4 acc[2][4];
#pragma unroll
  for (int ct = 0; ct < 2; ++ct)
#pragma unroll
    for (int nt_ = 0; nt_ < 4; ++nt_) acc[ct][nt_] = (floatx4)(0.f);

  GEMM_MFMA_SWAPPED(64, 72, 72)
  GEMM_WRITE_H_SWAPPED()
  GEMM_SCORE_SWAPPED()
}

// Layer-2 GEMM: bf16 X (K=128), LDS-staged A + B.
__global__ __launch_bounds__(256) void gemm_score_kernel(const unsigned short* __restrict__ X,
                                                         const unsigned short* __restrict__ Wb,
                                                         const float* __restrict__ a_s,
                                                         const float* __restrict__ a_d,
                                                         unsigned short* __restrict__ H,
                                                         float* __restrict__ ssc,
                                                         float* __restrict__ dsc,
                                                         int n) {
  __shared__ unsigned short As[64 * 136];
  __shared__ unsigned short Bs[128 * 136];
  const int tid = threadIdx.x;
  const int w = tid >> 6;
  const int lane = tid & 63;
  const int m0 = blockIdx.x * 64;
  const int quad = lane >> 4;
  const int l15 = lane & 15;

#pragma unroll
  for (int it = 0; it < 4; ++it) {
    const int idx = it * 256 + tid;
    const int row = idx >> 4;
    const int c8 = (idx & 15) * 8;
    const int grow = min(m0 + row, n - 1);
    short8 v = *(const short8*)(X + (size_t)grow * 128 + c8);
    *(short8*)(&As[row * 136 + c8]) = v;
  }
#pragma unroll
  for (int it = 0; it < 8; ++it) {
    const int idx = it * 256 + tid;
    const int row = idx >> 4;
    const int c8 = (idx & 15) * 8;
    short8 v = *(const short8*)(Wb + (size_t)row * 128 + c8);
    *(short8*)(&Bs[row * 136 + c8]) = v;
  }
  __syncthreads();

  floatx4 acc[2][4];
#pragma unroll
  for (int ct = 0; ct < 2; ++ct)
#pragma unroll
    for (int nt_ = 0; nt_ < 4; ++nt_) acc[ct][nt_] = (floatx4)(0.f);

  GEMM_MFMA_SWAPPED(128, 136, 136)
  GEMM_WRITE_H_SWAPPED()
  GEMM_SCORE_SWAPPED()
}

__device__ __forceinline__ float leaky02(float a) { return a > 0.f ? a : 0.2f * a; }
__device__ __forceinline__ float sel4(float4 v, int h) {
  return (h == 0) ? v.x : (h == 1) ? v.y : (h == 2) ? v.z : v.w;
}

// 1 wave per node (R8/R16 form — measured optimum). Phase B unroll-8,
// packed-fp32 accumulate.
__global__ __launch_bounds__(256) void agg_kernel(const unsigned short* __restrict__ hin,
                                                  const float* __restrict__ ssc,
                                                  const float* __restrict__ dsc,
                                                  const unsigned short* __restrict__ aeS,
                                                  const int* __restrict__ offs,
                                                  const int* __restrict__ srcS,
                                                  const float* __restrict__ bias,
                                                  unsigned short* __restrict__ hout, int n) {
  __shared__ int sbuf[4][64];
  __shared__ float pbuf[4][256];
  const int tid = threadIdx.x;
  const int wv = tid >> 6;
  const int lane = tid & 63;
  const int node = blockIdx.x * 4 + wv;
  if (node >= n) return;
  const int l32 = lane & 31;
  const int half = lane >> 5;
  const int ch4 = l32 * 4;
  const int headB = l32 >> 3;
  const float4 dv = *(const float4*)(dsc + (size_t)node * 4);
  float4 l4 = make_float4(0.f, 0.f, 0.f, 0.f);
  float4 sa = make_float4(0.f, 0.f, 0.f, 0.f);
  floatx2 acc01 = (floatx2)(0.f);
  floatx2 acc23 = (floatx2)(0.f);
  const int j0 = offs[node], j1 = offs[node + 1];

  for (int jc = j0; jc < j1; jc += 64) {
    const int len = min(64, j1 - jc);
    float4 p4 = make_float4(0.f, 0.f, 0.f, 0.f);
    int sv = 0;
    if (lane < len) {
      const int j = jc + lane;
      sv = srcS[j];
      const ushort4 aq = *(const ushort4*)(aeS + (size_t)j * 4);
      const float4 ae4 = make_float4(bf2f(aq.x), bf2f(aq.y), bf2f(aq.z), bf2f(aq.w));
      const float4 ss4 = *(const float4*)(ssc + (size_t)sv * 4);
      sa.x += ae4.x; sa.y += ae4.y; sa.z += ae4.z; sa.w += ae4.w;
      p4.x = __expf(leaky02(ss4.x + dv.x + ae4.x));
      p4.y = __expf(leaky02(ss4.y + dv.y + ae4.y));
      p4.z = __expf(leaky02(ss4.z + dv.z + ae4.z));
      p4.w = __expf(leaky02(ss4.w + dv.w + ae4.w));
    }
    sbuf[wv][lane] = sv;
    *(float4*)(&pbuf[wv][lane * 4]) = p4;
    l4.x += p4.x; l4.y += p4.y; l4.z += p4.z; l4.w += p4.w;
    int k = 0;
    for (; k + 8 <= len; k += 8) {
      int s[4];
      float p[4];
      uint2 d[4];
#pragma unroll
      for (int u = 0; u < 4; ++u) {
        const int kk = k + 2 * u + half;
        s[u] = sbuf[wv][kk];
        p[u] = pbuf[wv][kk * 4 + headB];
      }
#pragma unroll
      for (int u = 0; u < 4; ++u)
        d[u] = *(const uint2*)(hin + (size_t)s[u] * 128 + ch4);
#pragma unroll
      for (int u = 0; u < 4; ++u) {
        floatx2 p2; p2.x = p[u]; p2.y = p[u];
        floatx2 h01, h23;
        h01.x = __uint_as_float(d[u].x << 16);
        h01.y = __uint_as_float(d[u].x & 0xFFFF0000u);
        h23.x = __uint_as_float(d[u].y << 16);
        h23.y = __uint_as_float(d[u].y & 0xFFFF0000u);
        acc01 += p2 * h01;
        acc23 += p2 * h23;
      }
    }
    for (; k < len; k += 2) {
      int kk = k + half;
      if (kk < len) {
        int s = sbuf[wv][kk];
        float p = pbuf[wv][kk * 4 + headB];
        uint2 d = *(const uint2*)(hin + (size_t)s * 128 + ch4);
        floatx2 p2; p2.x = p; p2.y = p;
        floatx2 h01, h23;
        h01.x = __uint_as_float(d.x << 16);
        h01.y = __uint_as_float(d.x & 0xFFFF0000u);
        h23.x = __uint_as_float(d.y << 16);
        h23.y = __uint_as_float(d.y & 0xFFFF0000u);
        acc01 += p2 * h01;
        acc23 += p2 * h23;
      }
    }
  }

  float acc[4] = {acc01.x, acc01.y, acc23.x, acc23.y};
#pragma unroll
  for (int off = 32; off; off >>= 1) {
    sa.x += __shfl_xor(sa.x, off);
    sa.y += __shfl_xor(sa.y, off);
    sa.z += __shfl_xor(sa.z, off);
    sa.w += __shfl_xor(sa.w, off);
    l4.x += __shfl_xor(l4.x, off);
    l4.y += __shfl_xor(l4.y, off);
    l4.z += __shfl_xor(l4.z, off);
    l4.w += __shfl_xor(l4.w, off);
  }
#pragma unroll
  for (int i = 0; i < 4; ++i) acc[i] += __shfl_xor(acc[i], 32);

  const int deg = j1 - j0;
  const float invd = 1.f / fmaxf((float)deg, 1.f);
  const float ssn = ssc[(size_t)node * 4 + headB];
  const float aloop = leaky02(ssn + sel4(dv, headB) + sel4(sa, headB) * invd);
  const float pl = __expf(aloop);
  const float lF = sel4(l4, headB) + pl;
  const uint2 hd = *(const uint2*)(hin + (size_t)node * 128 + ch4);
  const float hv0 = __uint_as_float(hd.x << 16);
  const float hv1 = __uint_as_float(hd.x & 0xFFFF0000u);
  const float hv2 = __uint_as_float(hd.y << 16);
  const float hv3 = __uint_as_float(hd.y & 0xFFFF0000u);
  const float inv = 1.f / (lF + 1e-16f);
  const float4 bi = *(const float4*)(bias + ch4);
  const float o0 = fmaxf((acc[0] + pl * hv0) * inv + bi.x, 0.f);
  const float o1 = fmaxf((acc[1] + pl * hv1) * inv + bi.y, 0.f);
  const float o2 = fmaxf((acc[2] + pl * hv2) * inv + bi.z, 0.f);
  const float o3 = fmaxf((acc[3] + pl * hv3) * inv + bi.w, 0.f);
  if (half == 0) {
    ushort4 o;
    o.x = f2bf(o0); o.y = f2bf(o1); o.z = f2bf(o2); o.w = f2bf(o3);
    *(ushort4*)(hout + (size_t)node * 128 + ch4) = o;
  }
}

// Classifier as MFMA GEMM fused with log_softmax (R8).
__global__ __launch_bounds__(256) void classifier_kernel(const unsigned short* __restrict__ h,
                                                         const unsigned short* __restrict__ Whi,
                                                         const unsigned short* __restrict__ Wlo,
                                                         const float* __restrict__ blin,
                                                         float* __restrict__ out, int n) {
  const int w = threadIdx.x >> 6;
  const int lane = threadIdx.x & 63;
  const int quad = lane >> 4;
  const int l15 = lane & 15;
  const int row0 = blockIdx.x * 64 + w * 16;
  if (row0 >= n) return;
  int rowm = row0 + l15;
  if (rowm >= n) rowm = n - 1;
  floatx4 acc[3];
#pragma unroll
  for (int nt = 0; nt < 3; ++nt) acc[nt] = (floatx4)(0.f);
  const size_t hbase = (size_t)rowm * 128;
#pragma unroll
  for (int kc = 0; kc < 128; kc += 32) {
    const int koff = kc + (quad << 3);
    short8 a = *(const short8*)(h + hbase + koff);
#pragma unroll
    for (int nt = 0; nt < 3; ++nt) {
      short8 bh = *(const short8*)(Whi + (size_t)(nt * 16 + l15) * 128 + koff);
      short8 bl = *(const short8*)(Wlo + (size_t)(nt * 16 + l15) * 128 + koff);
      acc[nt] = __builtin_amdgcn_mfma_f32_16x16x32_bf16(a, bh, acc[nt], 0, 0, 0);
      acc[nt] = __builtin_amdgcn_mfma_f32_16x16x32_bf16(a, bl, acc[nt], 0, 0, 0);
    }
  }
  const float bl0 = blin[l15];
  const float bl1 = blin[16 + l15];
  const float bl2 = (l15 < 8) ? blin[32 + l15] : 0.f;
#pragma unroll
  for (int r = 0; r < 4; ++r) {
    const int rrow = row0 + (quad << 2) + r;
    const float v0 = acc[0][r] + bl0;
    const float v1 = acc[1][r] + bl1;
    const float v2 = (l15 < 8) ? (acc[2][r] + bl2) : -INFINITY;
    float m = fmaxf(v0, fmaxf(v1, v2));
#pragma unroll
    for (int off = 8; off; off >>= 1) m = fmaxf(m, __shfl_xor(m, off, 16));
    const float e2 = (l15 < 8) ? __expf(v2 - m) : 0.f;
    float s = __expf(v0 - m) + __expf(v1 - m) + e2;
#pragma unroll
    for (int off = 8; off; off >>= 1) s += __shfl_xor(s, off, 16);
    const float ls = m + __logf(s);
    if (rrow < n) {
      float* po = out + (size_t)rrow * 40;
      po[l15] = v0 - ls;
      po[16 + l15] = v1 - ls;
      if (l15 < 8) po[32 + l15] = v2 - ls;
    }
  }
}

extern "C" void kernel_launch(void* const* d_in, const int* in_sizes, int n_in,
                              void* d_out, int out_size, void* d_ws, size_t ws_size,
                              hipStream_t stream) {
  const float* x    = (const float*)d_in[0];
  const int*   eidx = (const int*)d_in[1];
  const float* ea   = (const float*)d_in[2];
  const float* W1   = (const float*)d_in[3];
  const float* as1  = (const float*)d_in[4];
  const float* ad1  = (const float*)d_in[5];
  const float* ae1w = (const float*)d_in[6];
  const float* We1  = (const float*)d_in[7];
  const float* b1   = (const float*)d_in[8];
  const float* W2   = (const float*)d_in[9];
  const float* as2  = (const float*)d_in[10];
  const float* ad2  = (const float*)d_in[11];
  const float* ae2w = (const float*)d_in[12];
  const float* We2  = (const float*)d_in[13];
  const float* b2   = (const float*)d_in[14];
  const float* Wlin = (const float*)d_in[15];
  const float* blin = (const float*)d_in[16];
  float* out = (float*)d_out;

  const int N = in_sizes[0] / 64;
  const int E = in_sizes[1] / 2;
  const int* src = eidx;
  const int* dst = eidx + E;
  const int NB = (N + 127) >> 7;
  const int gp = (E + CHUNK - 1) / CHUNK;

  char* wsb = (char*)d_ws;
  size_t off = 0;
  auto alloc = [&](size_t bytes) -> void* {
    void* p = wsb + off;
    off = (off + bytes + 255) & ~(size_t)255;
    return p;
  };
  int* bucketCnt  = (int*)alloc(512 * 4);
  int* bucketOffs = (int*)alloc(513 * 4);
  int* bucketPos  = (int*)alloc(512 * 4);
  int* offs       = (int*)alloc((size_t)(N + 1) * 4);
  int* chunkHist  = (int*)alloc((size_t)gp * 512 * 4);
  uint2* aeS1     = (uint2*)alloc((size_t)E * 8);
  uint2* aeS2     = (uint2*)alloc((size_t)E * 8);
  void* regC      = alloc((size_t)E * 16);          // binned16 -> hA
  int4* binned16  = (int4*)regC;
  unsigned short* hA = (unsigned short*)regC;       // N*256 <= E*16
  int* binned4    = (int*)alloc((size_t)E * 4);
  unsigned char* dlArr = (unsigned char*)alloc((size_t)E);
  int* srcS       = (int*)alloc((size_t)E * 4);
  unsigned short* Wb1 = (unsigned short*)alloc(128 * 64 * 2);
  unsigned short* Wb2 = (unsigned short*)alloc(128 * 128 * 2);
  unsigned short* Wlh = (unsigned short*)alloc(48 * 128 * 2);
  unsigned short* Wll = (unsigned short*)alloc(48 * 128 * 2);
  float* ssc      = (float*)alloc((size_t)N * 4 * 4);
  float* dsc      = (float*)alloc((size_t)N * 4 * 4);
  unsigned short* hB = (unsigned short*)alloc((size_t)N * 128 * 2);

  const int gg = (N + 63) / 64;
  const int gs = (N + 3) / 4;
  const int ncvt = 128 * 64 + 128 * 128 + 48 * 128;

  // ---- CSR bucket sort with fused alpha projection ----
  hipMemsetAsync(bucketCnt, 0, 512 * 4, stream);
  hist_kernel<<<gp, 512, 0, stream>>>(dst, bucketCnt, chunkHist, E, NB);
  scanB_kernel<<<1, 512, 0, stream>>>(bucketCnt, bucketOffs, bucketPos, offs, NB, N, E);
  partB_kernel<<<gp, 512, 0, stream>>>(src, dst, ea, ae1w, We1, ae2w, We2, chunkHist,
                                       bucketPos, binned16, binned4, dlArr, E, NB);
  passC_kernel<<<NB, 256, 0, stream>>>(binned16, binned4, dlArr, bucketOffs, srcS,
                                       aeS1, aeS2, offs, N);

  // ---- weight conversions (one kernel) ----
  cvtall_kernel<<<(ncvt + 255) / 256, 256, 0, stream>>>(W1, Wb1, W2, Wb2, Wlin, Wlh, Wll);

  // ---- layer 1 (gemm + fused score) ----
  gemm_score_f32_kernel<<<gg, 256, 0, stream>>>(x, Wb1, as1, ad1, hA, ssc, dsc, N);
  agg_kernel<<<gs, 256, 0, stream>>>(hA, ssc, dsc, (const unsigned short*)aeS1, offs, srcS, b1, hB, N);

  // ---- layer 2 (gemm + fused score) ----
  gemm_score_kernel<<<gg, 256, 0, stream>>>(hB, Wb2, as2, ad2, hA, ssc, dsc, N);
  agg_kernel<<<gs, 256, 0, stream>>>(hA, ssc, dsc, (const unsigned short*)aeS2, offs, srcS, b2, hB, N);

  // ---- classifier + log_softmax ----
  classifier_kernel<<<gg, 256, 0, stream>>>(hB, Wlh, Wll, blin, out, N);
}

// Round 17
// 449.621 us; speedup vs baseline: 1.1596x; 1.0002x over previous
//
#include <hip/hip_runtime.h>
#include <hip/hip_bf16.h>
#include <math.h>

// ---------------------------------------------------------------------------
// GAT 2-layer + classifier.
// R24: R23 base (449.7us best) + passC treated with the same medicine that
//      worked on partB: (1) count pass reads dlArr as aligned uchar4 (4x
//      fewer iters, full-width requests); (2) scatter loop 2-deep prefetch
//      (next binned16/binned4 in flight during current edge's LDS atomic +
//      3 scatter writes). partB/agg/gemms/classifier/hist/scanB unchanged.
// ---------------------------------------------------------------------------

#define CHUNK 2048

typedef __attribute__((ext_vector_type(8))) short short8;
typedef __attribute__((ext_vector_type(4))) float floatx4;
typedef __attribute__((ext_vector_type(2))) float floatx2;

__device__ __forceinline__ unsigned short f2bf(float f) {
  unsigned u = __float_as_uint(f);
  unsigned r = u + 0x7FFFu + ((u >> 16) & 1u);
  return (unsigned short)(r >> 16);
}
__device__ __forceinline__ float bf2f(unsigned short b) {
  return __uint_as_float(((unsigned)b) << 16);
}

__global__ __launch_bounds__(512) void hist_kernel(const int* __restrict__ dst,
                                                   int* __restrict__ bucketCnt,
                                                   int* __restrict__ chunkHist,
                                                   int E, int NB) {
  __shared__ int hist[512];
  const int tid = threadIdx.x;
  hist[tid] = 0;
  __syncthreads();
  const int e0 = blockIdx.x * CHUNK, e1 = min(e0 + CHUNK, E);
  for (int e = e0 + tid; e < e1; e += 512) atomicAdd(&hist[dst[e] >> 7], 1);
  __syncthreads();
  chunkHist[(size_t)blockIdx.x * 512 + tid] = hist[tid];
  if (tid < NB && hist[tid]) atomicAdd(&bucketCnt[tid], hist[tid]);
}

__global__ __launch_bounds__(512) void scanB_kernel(const int* __restrict__ bucketCnt,
                                                    int* __restrict__ bucketOffs,
                                                    int* __restrict__ bucketPos,
                                                    int* __restrict__ offs,
                                                    int NB, int N, int E) {
  __shared__ int sc[512];
  const int tid = threadIdx.x;
  const int v = (tid < NB) ? bucketCnt[tid] : 0;
  sc[tid] = v;
  __syncthreads();
  for (int off = 1; off < 512; off <<= 1) {
    int t = (tid >= off) ? sc[tid - off] : 0;
    __syncthreads();
    sc[tid] += t;
    __syncthreads();
  }
  const int excl = sc[tid] - v;
  if (tid < NB) { bucketOffs[tid] = excl; bucketPos[tid] = excl; }
  if (tid == 0) { bucketOffs[NB] = E; offs[N] = E; }
}

// Staged bucket partition fused with alpha projection (R23 form: chunkHist
// load + shfl scan + 2-deep prefetch + packed bucket id, no binary search).
__global__ __launch_bounds__(512) void partB_kernel(const int* __restrict__ src,
                                                    const int* __restrict__ dst,
                                                    const float* __restrict__ ea,
                                                    const float* __restrict__ ae1,
                                                    const float* __restrict__ We1,
                                                    const float* __restrict__ ae2,
                                                    const float* __restrict__ We2,
                                                    const int* __restrict__ chunkHist,
                                                    int* __restrict__ bucketPos,
                                                    int4* __restrict__ binned16,
                                                    int* __restrict__ binned4,
                                                    unsigned char* __restrict__ dlArr,
                                                    int E, int NB) {
  __shared__ float wa[128];
  __shared__ int lbase[513], gbase[512], lcnt[512];
  __shared__ int waveSum[8];
  __shared__ int4 stg16[CHUNK];
  __shared__ int stg4[CHUNK];
  const int tid = threadIdx.x;
  const int wv = tid >> 6;
  const int lane = tid & 63;
  const int e0 = blockIdx.x * CHUNK;
  const int e1 = min(e0 + CHUNK, E);
  lcnt[tid] = 0;
  if (tid < 128) {
    const float* aev = (tid < 64) ? ae1 : ae2;
    const float* Wev = (tid < 64) ? We1 : We2;
    const int h = (tid >> 4) & 3;
    const int d = tid & 15;
    float s = 0.f;
#pragma unroll
    for (int c = 0; c < 32; ++c) s += aev[h * 32 + c] * Wev[(h * 32 + c) * 16 + d];
    wa[tid] = s;
  }
  const int hv = chunkHist[(size_t)blockIdx.x * 512 + tid];
  int v = hv;
#pragma unroll
  for (int off = 1; off < 64; off <<= 1) {
    int t = __shfl_up(v, off);
    if (lane >= off) v += t;
  }
  if (lane == 63) waveSum[wv] = v;
  __syncthreads();
  int woff = 0;
#pragma unroll
  for (int i = 0; i < 8; ++i) woff += (i < wv) ? waveSum[i] : 0;
  lbase[tid + 1] = v + woff;
  if (tid == 0) lbase[0] = 0;
  if (tid < NB && hv > 0) gbase[tid] = atomicAdd(&bucketPos[tid], hv);
  __syncthreads();
  // phase 2: stage full payload with 2-deep prefetch
  {
    int e = e0 + tid;
    bool valid = (e < e1);
    int dcur = 0, scur = 0;
    float4 qa, qb, qc, qd;
    if (valid) {
      dcur = dst[e]; scur = src[e];
      const float4* p = (const float4*)(ea + (size_t)e * 16);
      qa = p[0]; qb = p[1]; qc = p[2]; qd = p[3];
    }
    while (valid) {
      const int en = e + 512;
      const bool vnext = (en < e1);
      int dnxt = 0, snxt = 0;
      float4 na, nb, nc, nd;
      if (vnext) {
        dnxt = dst[en]; snxt = src[en];
        const float4* p = (const float4*)(ea + (size_t)en * 16);
        na = p[0]; nb = p[1]; nc = p[2]; nd = p[3];
      }
      const int b = dcur >> 7;
      const int lr = atomicAdd(&lcnt[b], 1);
      float v16[16] = {qa.x, qa.y, qa.z, qa.w, qb.x, qb.y, qb.z, qb.w,
                       qc.x, qc.y, qc.z, qc.w, qd.x, qd.y, qd.z, qd.w};
      unsigned short rr[8];
#pragma unroll
      for (int h = 0; h < 8; ++h) {
        float sm = 0.f;
#pragma unroll
        for (int d2 = 0; d2 < 16; ++d2) sm += v16[d2] * wa[h * 16 + d2];
        rr[h] = f2bf(sm);
      }
      int4 pv;
      pv.x = (int)(((unsigned)(scur & 0xFFFF)) | ((unsigned)(dcur & 127) << 16) |
                   ((unsigned)b << 23));
      pv.y = (int)(((unsigned)rr[1] << 16) | rr[0]);
      pv.z = (int)(((unsigned)rr[3] << 16) | rr[2]);
      pv.w = (int)(((unsigned)rr[5] << 16) | rr[4]);
      const int sp = lbase[b] + lr;
      stg16[sp] = pv;
      stg4[sp] = (int)(((unsigned)rr[7] << 16) | rr[6]);
      e = en; valid = vnext; dcur = dnxt; scur = snxt;
      qa = na; qb = nb; qc = nc; qd = nd;
    }
  }
  __syncthreads();
  // phase 3: ordered scatter; bucket id read from payload
  const int total = e1 - e0;
  for (int t = tid; t < total; t += 512) {
    const int4 pv = stg16[t];
    const int b = (int)(((unsigned)pv.x) >> 23);
    const int g = gbase[b] + (t - lbase[b]);
    binned16[g] = pv;
    binned4[g] = stg4[t];
    dlArr[g] = (unsigned char)((pv.x >> 16) & 127);
  }
}

// Sort within bucket by dst; scatter srcS + both alpha arrays.
// R24: uchar4 count pass + 2-deep prefetch scatter.
__global__ __launch_bounds__(256) void passC_kernel(const int4* __restrict__ binned16,
                                                    const int* __restrict__ binned4,
                                                    const unsigned char* __restrict__ dlArr,
                                                    const int* __restrict__ bucketOffs,
                                                    int* __restrict__ srcS,
                                                    uint2* __restrict__ aeS1,
                                                    uint2* __restrict__ aeS2,
                                                    int* __restrict__ offs, int N) {
  __shared__ int cnt[128], dbase[129], dpos[128];
  const int tid = threadIdx.x;
  const int b = blockIdx.x;
  const int bo = bucketOffs[b], be = bucketOffs[b + 1];
  const int m = be - bo;
  if (tid < 128) { cnt[tid] = 0; dpos[tid] = 0; }
  __syncthreads();
  // count pass: aligned uchar4 body with scalar head/tail
  {
    const unsigned char* dp = dlArr + bo;
    const int head = (int)((4 - ((uintptr_t)dp & 3)) & 3);
    const int hcnt = min(head, m);
    if (tid < hcnt) atomicAdd(&cnt[dp[tid]], 1);
    const int mb = (m - hcnt) >> 2;
    const unsigned* dp4 = (const unsigned*)(dp + hcnt);
    for (int t4 = tid; t4 < mb; t4 += 256) {
      const unsigned u = dp4[t4];
      atomicAdd(&cnt[u & 127], 1);
      atomicAdd(&cnt[(u >> 8) & 127], 1);
      atomicAdd(&cnt[(u >> 16) & 127], 1);
      atomicAdd(&cnt[(u >> 24) & 127], 1);
    }
    for (int t = hcnt + mb * 4 + tid; t < m; t += 256) atomicAdd(&cnt[dp[t]], 1);
  }
  __syncthreads();
  for (int off = 1; off < 128; off <<= 1) {
    int t = (tid < 128 && tid >= (unsigned)off) ? cnt[tid - off] : 0;
    __syncthreads();
    if (tid < 128) cnt[tid] += t;
    __syncthreads();
  }
  if (tid == 0) dbase[0] = 0;
  if (tid < 128) dbase[tid + 1] = cnt[tid];
  __syncthreads();
  const int dcnt = min(128, N - (b << 7));
  if (tid < dcnt) offs[(b << 7) + tid] = bo + dbase[tid];
  // scatter with 2-deep prefetch
  {
    int t = tid;
    if (t < m) {
      int4 v = binned16[bo + t];
      int w4 = binned4[bo + t];
      while (true) {
        const int tn = t + 256;
        const bool more = (tn < m);
        int4 vn;
        int w4n = 0;
        if (more) { vn = binned16[bo + tn]; w4n = binned4[bo + tn]; }
        const int dl = (v.x >> 16) & 127;
        const int p = dbase[dl] + atomicAdd(&dpos[dl], 1);
        srcS[bo + p] = v.x & 0xFFFF;
        aeS1[bo + p] = make_uint2((unsigned)v.y, (unsigned)v.z);
        aeS2[bo + p] = make_uint2((unsigned)v.w, (unsigned)w4);
        if (!more) break;
        t = tn; v = vn; w4 = w4n;
      }
    }
  }
}

// W1 -> bf16, W2 -> bf16, Wlin -> padded [48][128] bf16 hi+lo, one kernel.
__global__ __launch_bounds__(256) void cvtall_kernel(const float* __restrict__ W1,
                                                     unsigned short* __restrict__ Wb1,
                                                     const float* __restrict__ W2,
                                                     unsigned short* __restrict__ Wb2,
                                                     const float* __restrict__ Wlin,
                                                     unsigned short* __restrict__ whi,
                                                     unsigned short* __restrict__ wlo) {
  const int n1 = 128 * 64, n2 = 128 * 128, n3 = 48 * 128;
  int i = blockIdx.x * 256 + threadIdx.x;
  if (i < n1) {
    Wb1[i] = f2bf(W1[i]);
  } else if (i < n1 + n2) {
    Wb2[i - n1] = f2bf(W2[i - n1]);
  } else if (i < n1 + n2 + n3) {
    const int j = i - n1 - n2;
    float v = (j < 40 * 128) ? Wlin[j] : 0.f;
    unsigned short h = f2bf(v);
    whi[j] = h;
    wlo[j] = f2bf(v - bf2f(h));
  }
}

// Swapped-operand MFMA body (R16).
#define GEMM_MFMA_SWAPPED(KTOT, PA, PB)                                            \
  {                                                                                \
    for (int kc = 0; kc < (KTOT); kc += 32) {                                      \
      const int koff = kc + (quad << 3);                                           \
      short8 aw[2], bx[4];                                                         \
      _Pragma("unroll") for (int ct = 0; ct < 2; ++ct)                             \
        aw[ct] = *(const short8*)(&Bs[(w * 32 + ct * 16 + l15) * (PB) + koff]);    \
      _Pragma("unroll") for (int nt_ = 0; nt_ < 4; ++nt_)                          \
        bx[nt_] = *(const short8*)(&As[(nt_ * 16 + l15) * (PA) + koff]);           \
      _Pragma("unroll") for (int ct = 0; ct < 2; ++ct)                             \
        _Pragma("unroll") for (int nt_ = 0; nt_ < 4; ++nt_)                        \
          acc[ct][nt_] =                                                           \
              __builtin_amdgcn_mfma_f32_16x16x32_bf16(aw[ct], bx[nt_],             \
                                                      acc[ct][nt_], 0, 0, 0);      \
    }                                                                              \
  }

#define GEMM_WRITE_H_SWAPPED()                                                     \
  {                                                                                \
    _Pragma("unroll") for (int nt_ = 0; nt_ < 4; ++nt_) {                          \
      const int node = m0 + nt_ * 16 + l15;                                        \
      if (node < n) {                                                              \
        _Pragma("unroll") for (int ct = 0; ct < 2; ++ct) {                         \
          const int ch = w * 32 + ct * 16 + (quad << 2);                           \
          ushort4 o;                                                               \
          o.x = f2bf(acc[ct][nt_][0]); o.y = f2bf(acc[ct][nt_][1]);                \
          o.z = f2bf(acc[ct][nt_][2]); o.w = f2bf(acc[ct][nt_][3]);                \
          *(ushort4*)(H + (size_t)node * 128 + ch) = o;                            \
        }                                                                          \
      }                                                                            \
    }                                                                              \
  }

#define GEMM_SCORE_SWAPPED()                                                       \
  {                                                                                \
    float asv[2][4], adv[2][4];                                                    \
    _Pragma("unroll") for (int ct = 0; ct < 2; ++ct)                               \
      _Pragma("unroll") for (int r = 0; r < 4; ++r) {                              \
        const int c = w * 32 + ct * 16 + (quad << 2) + r;                          \
        asv[ct][r] = a_s[c]; adv[ct][r] = a_d[c];                                  \
      }                                                                            \
    _Pragma("unroll") for (int nt_ = 0; nt_ < 4; ++nt_) {                          \
      float ps = 0.f, pd = 0.f;                                                    \
      _Pragma("unroll") for (int ct = 0; ct < 2; ++ct)                             \
        _Pragma("unroll") for (int r = 0; r < 4; ++r) {                            \
          ps += acc[ct][nt_][r] * asv[ct][r];                                      \
          pd += acc[ct][nt_][r] * adv[ct][r];                                      \
        }                                                                          \
      ps += __shfl_xor(ps, 16); ps += __shfl_xor(ps, 32);                          \
      pd += __shfl_xor(pd, 16); pd += __shfl_xor(pd, 32);                          \
      if (lane < 16) {                                                             \
        const int node = m0 + nt_ * 16 + lane;                                     \
        if (node < n) {                                                            \
          ssc[(size_t)node * 4 + w] = ps;                                          \
          dsc[(size_t)node * 4 + w] = pd;                                          \
        }                                                                          \
      }                                                                            \
    }                                                                              \
  }

// Layer-1 GEMM: fp32 X (K=64), LDS-staged A (convert during stage) + B.
__global__ __launch_bounds__(256) void gemm_score_f32_kernel(const float* __restrict__ X,
                                                             const unsigned short* __restrict__ Wb,
                                                             const float* __restrict__ a_s,
                                                             const float* __restrict__ a_d,
                                                             unsigned short* __restrict__ H,
                                                             float* __restrict__ ssc,
                                                             float* __restrict__ dsc,
                                                             int n) {
  __shared__ unsigned short As[64 * 72];
  __shared__ unsigned short Bs[128 * 72];
  const int tid = threadIdx.x;
  const int w = tid >> 6;
  const int lane = tid & 63;
  const int m0 = blockIdx.x * 64;
  const int quad = lane >> 4;
  const int l15 = lane & 15;

#pragma unroll
  for (int it = 0; it < 4; ++it) {
    const int idx = it * 256 + tid;
    const int row = idx >> 4;
    const int c4 = (idx & 15) * 4;
    const int grow = min(m0 + row, n - 1);
    const float4 q = *(const float4*)(X + (size_t)grow * 64 + c4);
    unsigned short* dstp = &As[row * 72 + c4];
    dstp[0] = f2bf(q.x); dstp[1] = f2bf(q.y); dstp[2] = f2bf(q.z); dstp[3] = f2bf(q.w);
  }
#pragma unroll
  for (int it = 0; it < 4; ++it) {
    const int idx = it * 256 + tid;
    const int row = idx >> 3;
    const int c8 = (idx & 7) * 8;
    short8 v = *(const short8*)(Wb + (size_t)row * 64 + c8);
    *(short8*)(&Bs[row * 72 + c8]) = v;
  }
  __syncthreads();

  floatx4 acc[2][4];
#pragma unroll
  for (int ct = 0; ct < 2; ++ct)
#pragma unroll
    for (int nt_ = 0; nt_ < 4; ++nt_) acc[ct][nt_] = (floatx4)(0.f);

  GEMM_MFMA_SWAPPED(64, 72, 72)
  GEMM_WRITE_H_SWAPPED()
  GEMM_SCORE_SWAPPED()
}

// Layer-2 GEMM: bf16 X (K=128), LDS-staged A + B.
__global__ __launch_bounds__(256) void gemm_score_kernel(const unsigned short* __restrict__ X,
                                                         const unsigned short* __restrict__ Wb,
                                                         const float* __restrict__ a_s,
                                                         const float* __restrict__ a_d,
                                                         unsigned short* __restrict__ H,
                                                         float* __restrict__ ssc,
                                                         float* __restrict__ dsc,
                                                         int n) {
  __shared__ unsigned short As[64 * 136];
  __shared__ unsigned short Bs[128 * 136];
  const int tid = threadIdx.x;
  const int w = tid >> 6;
  const int lane = tid & 63;
  const int m0 = blockIdx.x * 64;
  const int quad = lane >> 4;
  const int l15 = lane & 15;

#pragma unroll
  for (int it = 0; it < 4; ++it) {
    const int idx = it * 256 + tid;
    const int row = idx >> 4;
    const int c8 = (idx & 15) * 8;
    const int grow = min(m0 + row, n - 1);
    short8 v = *(const short8*)(X + (size_t)grow * 128 + c8);
    *(short8*)(&As[row * 136 + c8]) = v;
  }
#pragma unroll
  for (int it = 0; it < 8; ++it) {
    const int idx = it * 256 + tid;
    const int row = idx >> 4;
    const int c8 = (idx & 15) * 8;
    short8 v = *(const short8*)(Wb + (size_t)row * 128 + c8);
    *(short8*)(&Bs[row * 136 + c8]) = v;
  }
  __syncthreads();

  floatx4 acc[2][4];
#pragma unroll
  for (int ct = 0; ct < 2; ++ct)
#pragma unroll
    for (int nt_ = 0; nt_ < 4; ++nt_) acc[ct][nt_] = (floatx4)(0.f);

  GEMM_MFMA_SWAPPED(128, 136, 136)
  GEMM_WRITE_H_SWAPPED()
  GEMM_SCORE_SWAPPED()
}

__device__ __forceinline__ float leaky02(float a) { return a > 0.f ? a : 0.2f * a; }
__device__ __forceinline__ float sel4(float4 v, int h) {
  return (h == 0) ? v.x : (h == 1) ? v.y : (h == 2) ? v.z : v.w;
}

// 1 wave per node (R8/R16 form — measured optimum). Phase B unroll-8,
// packed-fp32 accumulate.
__global__ __launch_bounds__(256) void agg_kernel(const unsigned short* __restrict__ hin,
                                                  const float* __restrict__ ssc,
                                                  const float* __restrict__ dsc,
                                                  const unsigned short* __restrict__ aeS,
                                                  const int* __restrict__ offs,
                                                  const int* __restrict__ srcS,
                                                  const float* __restrict__ bias,
                                                  unsigned short* __restrict__ hout, int n) {
  __shared__ int sbuf[4][64];
  __shared__ float pbuf[4][256];
  const int tid = threadIdx.x;
  const int wv = tid >> 6;
  const int lane = tid & 63;
  const int node = blockIdx.x * 4 + wv;
  if (node >= n) return;
  const int l32 = lane & 31;
  const int half = lane >> 5;
  const int ch4 = l32 * 4;
  const int headB = l32 >> 3;
  const float4 dv = *(const float4*)(dsc + (size_t)node * 4);
  float4 l4 = make_float4(0.f, 0.f, 0.f, 0.f);
  float4 sa = make_float4(0.f, 0.f, 0.f, 0.f);
  floatx2 acc01 = (floatx2)(0.f);
  floatx2 acc23 = (floatx2)(0.f);
  const int j0 = offs[node], j1 = offs[node + 1];

  for (int jc = j0; jc < j1; jc += 64) {
    const int len = min(64, j1 - jc);
    float4 p4 = make_float4(0.f, 0.f, 0.f, 0.f);
    int sv = 0;
    if (lane < len) {
      const int j = jc + lane;
      sv = srcS[j];
      const ushort4 aq = *(const ushort4*)(aeS + (size_t)j * 4);
      const float4 ae4 = make_float4(bf2f(aq.x), bf2f(aq.y), bf2f(aq.z), bf2f(aq.w));
      const float4 ss4 = *(const float4*)(ssc + (size_t)sv * 4);
      sa.x += ae4.x; sa.y += ae4.y; sa.z += ae4.z; sa.w += ae4.w;
      p4.x = __expf(leaky02(ss4.x + dv.x + ae4.x));
      p4.y = __expf(leaky02(ss4.y + dv.y + ae4.y));
      p4.z = __expf(leaky02(ss4.z + dv.z + ae4.z));
      p4.w = __expf(leaky02(ss4.w + dv.w + ae4.w));
    }
    sbuf[wv][lane] = sv;
    *(float4*)(&pbuf[wv][lane * 4]) = p4;
    l4.x += p4.x; l4.y += p4.y; l4.z += p4.z; l4.w += p4.w;
    int k = 0;
    for (; k + 8 <= len; k += 8) {
      int s[4];
      float p[4];
      uint2 d[4];
#pragma unroll
      for (int u = 0; u < 4; ++u) {
        const int kk = k + 2 * u + half;
        s[u] = sbuf[wv][kk];
        p[u] = pbuf[wv][kk * 4 + headB];
      }
#pragma unroll
      for (int u = 0; u < 4; ++u)
        d[u] = *(const uint2*)(hin + (size_t)s[u] * 128 + ch4);
#pragma unroll
      for (int u = 0; u < 4; ++u) {
        floatx2 p2; p2.x = p[u]; p2.y = p[u];
        floatx2 h01, h23;
        h01.x = __uint_as_float(d[u].x << 16);
        h01.y = __uint_as_float(d[u].x & 0xFFFF0000u);
        h23.x = __uint_as_float(d[u].y << 16);
        h23.y = __uint_as_float(d[u].y & 0xFFFF0000u);
        acc01 += p2 * h01;
        acc23 += p2 * h23;
      }
    }
    for (; k < len; k += 2) {
      int kk = k + half;
      if (kk < len) {
        int s = sbuf[wv][kk];
        float p = pbuf[wv][kk * 4 + headB];
        uint2 d = *(const uint2*)(hin + (size_t)s * 128 + ch4);
        floatx2 p2; p2.x = p; p2.y = p;
        floatx2 h01, h23;
        h01.x = __uint_as_float(d.x << 16);
        h01.y = __uint_as_float(d.x & 0xFFFF0000u);
        h23.x = __uint_as_float(d.y << 16);
        h23.y = __uint_as_float(d.y & 0xFFFF0000u);
        acc01 += p2 * h01;
        acc23 += p2 * h23;
      }
    }
  }

  float acc[4] = {acc01.x, acc01.y, acc23.x, acc23.y};
#pragma unroll
  for (int off = 32; off; off >>= 1) {
    sa.x += __shfl_xor(sa.x, off);
    sa.y += __shfl_xor(sa.y, off);
    sa.z += __shfl_xor(sa.z, off);
    sa.w += __shfl_xor(sa.w, off);
    l4.x += __shfl_xor(l4.x, off);
    l4.y += __shfl_xor(l4.y, off);
    l4.z += __shfl_xor(l4.z, off);
    l4.w += __shfl_xor(l4.w, off);
  }
#pragma unroll
  for (int i = 0; i < 4; ++i) acc[i] += __shfl_xor(acc[i], 32);

  const int deg = j1 - j0;
  const float invd = 1.f / fmaxf((float)deg, 1.f);
  const float ssn = ssc[(size_t)node * 4 + headB];
  const float aloop = leaky02(ssn + sel4(dv, headB) + sel4(sa, headB) * invd);
  const float pl = __expf(aloop);
  const float lF = sel4(l4, headB) + pl;
  const uint2 hd = *(const uint2*)(hin + (size_t)node * 128 + ch4);
  const float hv0 = __uint_as_float(hd.x << 16);
  const float hv1 = __uint_as_float(hd.x & 0xFFFF0000u);
  const float hv2 = __uint_as_float(hd.y << 16);
  const float hv3 = __uint_as_float(hd.y & 0xFFFF0000u);
  const float inv = 1.f / (lF + 1e-16f);
  const float4 bi = *(const float4*)(bias + ch4);
  const float o0 = fmaxf((acc[0] + pl * hv0) * inv + bi.x, 0.f);
  const float o1 = fmaxf((acc[1] + pl * hv1) * inv + bi.y, 0.f);
  const float o2 = fmaxf((acc[2] + pl * hv2) * inv + bi.z, 0.f);
  const float o3 = fmaxf((acc[3] + pl * hv3) * inv + bi.w, 0.f);
  if (half == 0) {
    ushort4 o;
    o.x = f2bf(o0); o.y = f2bf(o1); o.z = f2bf(o2); o.w = f2bf(o3);
    *(ushort4*)(hout + (size_t)node * 128 + ch4) = o;
  }
}

// Classifier as MFMA GEMM fused with log_softmax (R8).
__global__ __launch_bounds__(256) void classifier_kernel(const unsigned short* __restrict__ h,
                                                         const unsigned short* __restrict__ Whi,
                                                         const unsigned short* __restrict__ Wlo,
                                                         const float* __restrict__ blin,
                                                         float* __restrict__ out, int n) {
  const int w = threadIdx.x >> 6;
  const int lane = threadIdx.x & 63;
  const int quad = lane >> 4;
  const int l15 = lane & 15;
  const int row0 = blockIdx.x * 64 + w * 16;
  if (row0 >= n) return;
  int rowm = row0 + l15;
  if (rowm >= n) rowm = n - 1;
  floatx4 acc[3];
#pragma unroll
  for (int nt = 0; nt < 3; ++nt) acc[nt] = (floatx4)(0.f);
  const size_t hbase = (size_t)rowm * 128;
#pragma unroll
  for (int kc = 0; kc < 128; kc += 32) {
    const int koff = kc + (quad << 3);
    short8 a = *(const short8*)(h + hbase + koff);
#pragma unroll
    for (int nt = 0; nt < 3; ++nt) {
      short8 bh = *(const short8*)(Whi + (size_t)(nt * 16 + l15) * 128 + koff);
      short8 bl = *(const short8*)(Wlo + (size_t)(nt * 16 + l15) * 128 + koff);
      acc[nt] = __builtin_amdgcn_mfma_f32_16x16x32_bf16(a, bh, acc[nt], 0, 0, 0);
      acc[nt] = __builtin_amdgcn_mfma_f32_16x16x32_bf16(a, bl, acc[nt], 0, 0, 0);
    }
  }
  const float bl0 = blin[l15];
  const float bl1 = blin[16 + l15];
  const float bl2 = (l15 < 8) ? blin[32 + l15] : 0.f;
#pragma unroll
  for (int r = 0; r < 4; ++r) {
    const int rrow = row0 + (quad << 2) + r;
    const float v0 = acc[0][r] + bl0;
    const float v1 = acc[1][r] + bl1;
    const float v2 = (l15 < 8) ? (acc[2][r] + bl2) : -INFINITY;
    float m = fmaxf(v0, fmaxf(v1, v2));
#pragma unroll
    for (int off = 8; off; off >>= 1) m = fmaxf(m, __shfl_xor(m, off, 16));
    const float e2 = (l15 < 8) ? __expf(v2 - m) : 0.f;
    float s = __expf(v0 - m) + __expf(v1 - m) + e2;
#pragma unroll
    for (int off = 8; off; off >>= 1) s += __shfl_xor(s, off, 16);
    const float ls = m + __logf(s);
    if (rrow < n) {
      float* po = out + (size_t)rrow * 40;
      po[l15] = v0 - ls;
      po[16 + l15] = v1 - ls;
      if (l15 < 8) po[32 + l15] = v2 - ls;
    }
  }
}

extern "C" void kernel_launch(void* const* d_in, const int* in_sizes, int n_in,
                              void* d_out, int out_size, void* d_ws, size_t ws_size,
                              hipStream_t stream) {
  const float* x    = (const float*)d_in[0];
  const int*   eidx = (const int*)d_in[1];
  const float* ea   = (const float*)d_in[2];
  const float* W1   = (const float*)d_in[3];
  const float* as1  = (const float*)d_in[4];
  const float* ad1  = (const float*)d_in[5];
  const float* ae1w = (const float*)d_in[6];
  const float* We1  = (const float*)d_in[7];
  const float* b1   = (const float*)d_in[8];
  const float* W2   = (const float*)d_in[9];
  const float* as2  = (const float*)d_in[10];
  const float* ad2  = (const float*)d_in[11];
  const float* ae2w = (const float*)d_in[12];
  const float* We2  = (const float*)d_in[13];
  const float* b2   = (const float*)d_in[14];
  const float* Wlin = (const float*)d_in[15];
  const float* blin = (const float*)d_in[16];
  float* out = (float*)d_out;

  const int N = in_sizes[0] / 64;
  const int E = in_sizes[1] / 2;
  const int* src = eidx;
  const int* dst = eidx + E;
  const int NB = (N + 127) >> 7;
  const int gp = (E + CHUNK - 1) / CHUNK;

  char* wsb = (char*)d_ws;
  size_t off = 0;
  auto alloc = [&](size_t bytes) -> void* {
    void* p = wsb + off;
    off = (off + bytes + 255) & ~(size_t)255;
    return p;
  };
  int* bucketCnt  = (int*)alloc(512 * 4);
  int* bucketOffs = (int*)alloc(513 * 4);
  int* bucketPos  = (int*)alloc(512 * 4);
  int* offs       = (int*)alloc((size_t)(N + 1) * 4);
  int* chunkHist  = (int*)alloc((size_t)gp * 512 * 4);
  uint2* aeS1     = (uint2*)alloc((size_t)E * 8);
  uint2* aeS2     = (uint2*)alloc((size_t)E * 8);
  void* regC      = alloc((size_t)E * 16);          // binned16 -> hA
  int4* binned16  = (int4*)regC;
  unsigned short* hA = (unsigned short*)regC;       // N*256 <= E*16
  int* binned4    = (int*)alloc((size_t)E * 4);
  unsigned char* dlArr = (unsigned char*)alloc((size_t)E);
  int* srcS       = (int*)alloc((size_t)E * 4);
  unsigned short* Wb1 = (unsigned short*)alloc(128 * 64 * 2);
  unsigned short* Wb2 = (unsigned short*)alloc(128 * 128 * 2);
  unsigned short* Wlh = (unsigned short*)alloc(48 * 128 * 2);
  unsigned short* Wll = (unsigned short*)alloc(48 * 128 * 2);
  float* ssc      = (float*)alloc((size_t)N * 4 * 4);
  float* dsc      = (float*)alloc((size_t)N * 4 * 4);
  unsigned short* hB = (unsigned short*)alloc((size_t)N * 128 * 2);

  const int gg = (N + 63) / 64;
  const int gs = (N + 3) / 4;
  const int ncvt = 128 * 64 + 128 * 128 + 48 * 128;

  // ---- CSR bucket sort with fused alpha projection ----
  hipMemsetAsync(bucketCnt, 0, 512 * 4, stream);
  hist_kernel<<<gp, 512, 0, stream>>>(dst, bucketCnt, chunkHist, E, NB);
  scanB_kernel<<<1, 512, 0, stream>>>(bucketCnt, bucketOffs, bucketPos, offs, NB, N, E);
  partB_kernel<<<gp, 512, 0, stream>>>(src, dst, ea, ae1w, We1, ae2w, We2, chunkHist,
                                       bucketPos, binned16, binned4, dlArr, E, NB);
  passC_kernel<<<NB, 256, 0, stream>>>(binned16, binned4, dlArr, bucketOffs, srcS,
                                       aeS1, aeS2, offs, N);

  // ---- weight conversions (one kernel) ----
  cvtall_kernel<<<(ncvt + 255) / 256, 256, 0, stream>>>(W1, Wb1, W2, Wb2, Wlin, Wlh, Wll);

  // ---- layer 1 (gemm + fused score) ----
  gemm_score_f32_kernel<<<gg, 256, 0, stream>>>(x, Wb1, as1, ad1, hA, ssc, dsc, N);
  agg_kernel<<<gs, 256, 0, stream>>>(hA, ssc, dsc, (const unsigned short*)aeS1, offs, srcS, b1, hB, N);

  // ---- layer 2 (gemm + fused score) ----
  gemm_score_kernel<<<gg, 256, 0, stream>>>(hB, Wb2, as2, ad2, hA, ssc, dsc, N);
  agg_kernel<<<gs, 256, 0, stream>>>(hA, ssc, dsc, (const unsigned short*)aeS2, offs, srcS, b2, hB, N);

  // ---- classifier + log_softmax ----
  classifier_kernel<<<gg, 256, 0, stream>>>(hB, Wlh, Wll, blin, out, N);
}